// Round 1
// baseline (910.042 us; speedup 1.0000x reference)
//
#include <hip/hip_runtime.h>
#include <math.h>

#define NBATCH 16
#define NN 63
#define NP 64

// One block per batch element. 256 threads = 4 waves.
// Mapping M (elementwise/register state): w = tid>>6, lane = tid&63 (= column j),
// thread owns rows i = w + 4m, m = 0..15.
__global__ __launch_bounds__(256) void ged_kernel(
    const float* __restrict__ node_w, const float* __restrict__ edge_w,
    const int* __restrict__ A1g, const int* __restrict__ A2g,
    const int* __restrict__ l1g, const int* __restrict__ l2g,
    float* __restrict__ ged_out)
{
    const int b    = blockIdx.x;
    const int tid  = threadIdx.x;
    const int lane = tid & 63;
    const int w    = tid >> 6;

    __shared__ float Ws[NP][NP + 1];          // sinkhorn workspace (padded: col pass conflict-free)
    __shared__ float Yt[2][NP][NP];           // Y planes for 2 edge labels; [j][k ^ (j&31)] swizzle
    __shared__ unsigned char adj1e[NP][NP];   // packed (k | (label-1)<<6)
    __shared__ unsigned char adj2e[NP][NP];
    __shared__ short adj1n[NP], adj2n[NP];
    __shared__ float ncost[8][8];
    __shared__ float Qs[4][4];                // Q[a][b] = 2*ec[a][b] - 2*eid
    __shared__ float cns[29], ces[7];
    __shared__ int   l1s[NP], l2s[NP];
    __shared__ float rX[NP], cXs[NP], S1s[NP], S2s[NP];
    __shared__ float red[8];
    __shared__ float tshare;

    // ---- setup: relu'd weights ----
    if (tid < 29) cns[tid] = fmaxf(node_w[tid], 0.0f);
    if (tid < 7)  ces[tid] = fmaxf(edge_w[tid], 0.0f);
    __syncthreads();
    const float eid = ces[6];   // edge ins/del cost
    const float nid = cns[28];  // node ins/del cost

    // node cost table (triu_indices(8,k=1) row-major), Q table
    if (tid < 64) {
        int r = tid >> 3, c = tid & 7;
        float v = 0.0f;
        if (r != c) {
            int lo = r < c ? r : c, hi = r < c ? c : r;
            v = cns[lo * 7 - (lo * (lo - 1)) / 2 + (hi - lo - 1)];
        }
        ncost[r][c] = v;
    } else if (tid < 80) {
        int a = (tid - 64) >> 2, bb = tid & 3;
        float ec = 0.0f;
        if (a != bb) {
            int lo = a < bb ? a : bb, hi = a < bb ? bb : a;
            ec = ces[lo * 3 - (lo * (lo - 1)) / 2 + (hi - lo - 1)];
        }
        Qs[a][bb] = 2.0f * ec - 2.0f * eid;
    }
    if (tid >= 128 && tid < 192) {
        int i = tid - 128;
        l1s[i] = (i < NN) ? l1g[b * NN + i] : 0;
    } else if (tid >= 192) {
        int j = tid - 192;
        l2s[j] = (j < NN) ? l2g[b * NN + j] : 0;
    }
    // adjacency lists (padded row/col 63 are empty; diagonals are zero in input)
    if (tid < 64) {
        int j = tid, cnt = 0;
        if (j < NN) {
            const int* row = A2g + (size_t)b * NN * NN + (size_t)j * NN;
            for (int l = 0; l < NN; ++l) {
                int v = row[l];
                if (v != 0) adj2e[j][cnt++] = (unsigned char)(l | ((v - 1) << 6));
            }
        }
        adj2n[j] = (short)cnt;
    } else if (tid < 128) {
        int i = tid - 64, cnt = 0;
        if (i < NN) {
            const int* row = A1g + (size_t)b * NN * NN + (size_t)i * NN;
            for (int l = 0; l < NN; ++l) {
                int v = row[l];
                if (v != 0) adj1e[i][cnt++] = (unsigned char)(l | ((v - 1) << 6));
            }
        }
        adj1n[i] = (short)cnt;
    }
    __syncthreads();

    // ---- c matrix in registers + x0 seed ----
    float c_reg[16];
    #pragma unroll
    for (int m = 0; m < 16; ++m) {
        int i = w + (m << 2);
        float cv;
        if (i < NN && lane < NN) cv = ncost[l1s[i]][l2s[lane]];
        else cv = (i == NN && lane == NN) ? 0.0f : nid;
        c_reg[m] = cv;
        Ws[i][lane] = expf(-cv);
    }
    __syncthreads();

    // ---- sinkhorn on Ws (rows <63 row-normalized, then cols <63 col-normalized) ----
    auto sinkhorn = [&](int n_iter) {
        const int q  = tid & 3;
        const int rr = tid >> 2;
        const int c0 = q << 4;
        for (int it = 0; it < n_iter; ++it) {
            float s = 0.0f;
            if (rr < NN) {
                #pragma unroll
                for (int u = 0; u < 16; ++u) s += Ws[rr][c0 + u];
            }
            s += __shfl_xor(s, 1, 64);
            s += __shfl_xor(s, 2, 64);
            if (rr < NN) {
                float inv = 1.0f / s;
                #pragma unroll
                for (int u = 0; u < 16; ++u) Ws[rr][c0 + u] *= inv;
            }
            __syncthreads();
            s = 0.0f;
            if (rr < NN) {
                #pragma unroll
                for (int u = 0; u < 16; ++u) s += Ws[c0 + u][rr];
            }
            s += __shfl_xor(s, 1, 64);
            s += __shfl_xor(s, 2, 64);
            if (rr < NN) {
                float inv = 1.0f / s;
                #pragma unroll
                for (int u = 0; u < 16; ++u) Ws[c0 + u][rr] *= inv;
            }
            __syncthreads();
        }
    };

    // ---- out[m] = (D @ Ws)[i=w+4m, j=lane] ----
    auto matvec = [&](float* out) {
        {   // row sums rX[k] and col sums cXs[l] of Ws
            const int q  = tid & 3;
            const int rr = tid >> 2;
            const int c0 = q << 4;
            float s = 0.0f, s2 = 0.0f;
            #pragma unroll
            for (int u = 0; u < 16; ++u) { s += Ws[rr][c0 + u]; s2 += Ws[c0 + u][rr]; }
            s  += __shfl_xor(s, 1, 64);  s  += __shfl_xor(s, 2, 64);
            s2 += __shfl_xor(s2, 1, 64); s2 += __shfl_xor(s2, 2, 64);
            if (q == 0) { rX[rr] = s; cXs[rr] = s2; }
        }
        __syncthreads();
        if (tid < 64) {
            int j = tid, n = adj2n[j];
            float s = 0.0f;
            for (int e = 0; e < n; ++e) s += cXs[adj2e[j][e] & 63];
            S2s[j] = s;
        } else if (tid < 128) {
            int i = tid - 64, n = adj1n[i];
            float s = 0.0f;
            for (int e = 0; e < n; ++e) s += rX[adj1e[i][e] & 63];
            S1s[i] = s;
        }
        __syncthreads();
        #pragma unroll
        for (int m = 0; m < 16; ++m) out[m] = eid * (S1s[w + (m << 2)] + S2s[lane]);

        #pragma unroll
        for (int pass = 0; pass < 2; ++pass) {
            const int bv0 = pass * 2, bv1 = bv0 + 1;
            // stage1: lane = k, uniform j per wave-iteration (branches wave-uniform)
            for (int m = 0; m < 16; ++m) {
                int j = w + (m << 2);
                int n = adj2n[j];
                float a0 = 0.0f, a1 = 0.0f;
                for (int e = 0; e < n; ++e) {
                    int p = adj2e[j][e];
                    int bb = p >> 6;
                    if (bb == bv0)      a0 += Ws[lane][p & 63];
                    else if (bb == bv1) a1 += Ws[lane][p & 63];
                }
                int kk = lane ^ (j & 31);
                Yt[0][j][kk] = a0;
                Yt[1][j][kk] = a1;
            }
            __syncthreads();
            // stage2: lane = j; adj1[i] wave-uniform; Yt reads 2-way conflict (free)
            #pragma unroll
            for (int m = 0; m < 16; ++m) {
                int i = w + (m << 2);
                int n = adj1n[i];
                float acc = 0.0f;
                for (int e = 0; e < n; ++e) {
                    int p = adj1e[i][e];
                    int k = p & 63, a = p >> 6;
                    int kk = k ^ (lane & 31);
                    acc += Qs[a][bv0] * Yt[0][lane][kk] + Qs[a][bv1] * Yt[1][lane][kk];
                }
                out[m] += acc;
            }
            __syncthreads();
        }
    };

    sinkhorn(10);

    float x[16], dx[16], db[16];
    #pragma unroll
    for (int m = 0; m < 16; ++m) x[m] = Ws[w + (m << 2)][lane];
    matvec(dx);   // dx = D @ x0

    for (int it = 0; it < 15; ++it) {
        // g = c + dx (registers); W = exp(-g)
        #pragma unroll
        for (int m = 0; m < 16; ++m)
            Ws[w + (m << 2)][lane] = expf(-(c_reg[m] + dx[m]));
        __syncthreads();
        sinkhorn(5);          // Ws := b
        matvec(db);           // db = D @ b
        float dn = 0.0f, nm = 0.0f;
        #pragma unroll
        for (int m = 0; m < 16; ++m) {
            float d = Ws[w + (m << 2)][lane] - x[m];
            dn += d * (db[m] - dx[m]);          // d . (D d)
            nm += d * (c_reg[m] + dx[m]);       // d . g
        }
        #pragma unroll
        for (int off = 32; off >= 1; off >>= 1) {
            dn += __shfl_xor(dn, off, 64);
            nm += __shfl_xor(nm, off, 64);
        }
        if (lane == 0) { red[w] = dn; red[4 + w] = nm; }
        __syncthreads();
        if (tid == 0) {
            float den = red[0] + red[1] + red[2] + red[3];
            float num = red[4] + red[5] + red[6] + red[7];
            float t;
            if (den > 0.0f) t = fminf(fmaxf(-num / den, 0.0f), 1.0f);
            else            t = (num < 0.0f) ? 1.0f : 0.0f;
            tshare = t;
        }
        __syncthreads();
        float t = tshare;
        #pragma unroll
        for (int m = 0; m < 16; ++m) {
            float d = Ws[w + (m << 2)][lane] - x[m];
            x[m]  += t * d;
            dx[m] += t * (db[m] - dx[m]);   // D x_new tracked by linearity
        }
        // no barrier needed: remaining Ws accesses are owner-local until next exp+barrier
    }

    // ged = 0.5 * x.Dx + c.x
    float g = 0.0f;
    #pragma unroll
    for (int m = 0; m < 16; ++m) g += x[m] * (0.5f * dx[m] + c_reg[m]);
    #pragma unroll
    for (int off = 32; off >= 1; off >>= 1) g += __shfl_xor(g, off, 64);
    if (lane == 0) red[w] = g;
    __syncthreads();
    if (tid == 0) ged_out[b] = red[0] + red[1] + red[2] + red[3];
}

__global__ void norm_kernel(const float* __restrict__ g, float* __restrict__ out) {
    int t = threadIdx.x;
    if (t < NBATCH) {
        float mn = g[0], mx = g[0];
        #pragma unroll
        for (int i = 1; i < NBATCH; ++i) { mn = fminf(mn, g[i]); mx = fmaxf(mx, g[i]); }
        out[t] = (g[t] - mn) / (mx - mn);
    }
}

extern "C" void kernel_launch(void* const* d_in, const int* in_sizes, int n_in,
                              void* d_out, int out_size, void* d_ws, size_t ws_size,
                              hipStream_t stream) {
    (void)in_sizes; (void)n_in; (void)out_size; (void)ws_size;
    const float* node_w = (const float*)d_in[0];
    const float* edge_w = (const float*)d_in[1];
    const int*   A1     = (const int*)d_in[2];
    const int*   A2     = (const int*)d_in[3];
    const int*   l1     = (const int*)d_in[4];
    const int*   l2     = (const int*)d_in[5];
    float* ged = (float*)d_ws;
    ged_kernel<<<dim3(NBATCH), dim3(256), 0, stream>>>(node_w, edge_w, A1, A2, l1, l2, ged);
    norm_kernel<<<dim3(1), dim3(64), 0, stream>>>(ged, (float*)d_out);
}

// Round 2
// 275.544 us; speedup vs baseline: 3.3027x; 3.3027x over previous
//
#include <hip/hip_runtime.h>
#include <math.h>

#define NBATCH 16
#define NN 63
#define NP 64

// One block per batch element. 1024 threads = 16 waves.
// Register-state mapping: w = tid>>6 (wave), lane = tid&63 (= column j),
// thread owns rows i = w + 16m, m = 0..3.
__global__ __launch_bounds__(1024) void ged_kernel(
    const float* __restrict__ node_w, const float* __restrict__ edge_w,
    const int* __restrict__ A1g, const int* __restrict__ A2g,
    const int* __restrict__ l1g, const int* __restrict__ l2g,
    float* __restrict__ ged_out)
{
    const int b    = blockIdx.x;
    const int tid  = threadIdx.x;
    const int lane = tid & 63;
    const int w    = tid >> 6;

    __shared__ float Ws[NP][NP + 1];          // sinkhorn workspace (pad: col pass 2-way = free)
    __shared__ float Yt[2][NP][NP];           // Y planes (2 labels per pass); [j][k ^ (j&31)]
    __shared__ unsigned char adj1e[NP][NP];   // packed (k | (label-1)<<6)
    __shared__ unsigned char adj2e[NP][NP];   // label-sorted: labels {1,2} first, then {3,4}
    __shared__ int adj1n[NP], adj2n[NP], adj2s[NP];  // counts; adj2s = end of {1,2} section
    __shared__ float ncost[8][8];
    __shared__ float Qs[4][4];                // Q[a][b] = 2*ec[a][b] - 2*eid
    __shared__ float cns[29], ces[7];
    __shared__ int   l1s[NP], l2s[NP];
    __shared__ float rX[NP], cXs[NP], S1s[NP], S2s[NP];
    __shared__ float red[32];
    __shared__ float tshare;

    // ---- phase A: weights, labels, adjacency build (wave-parallel ballot) ----
    if (tid < 29) cns[tid] = fmaxf(node_w[tid], 0.0f);
    else if (tid >= 32 && tid < 39) ces[tid - 32] = fmaxf(edge_w[tid - 32], 0.0f);
    if (tid >= 256 && tid < 320) {
        int i = tid - 256;
        l1s[i] = (i < NN) ? l1g[b * NN + i] : 0;
    } else if (tid >= 320 && tid < 384) {
        int j = tid - 320;
        l2s[j] = (j < NN) ? l2g[b * NN + j] : 0;
    }
    {
        const unsigned long long lt = (1ull << lane) - 1ull;
        #pragma unroll
        for (int r = 0; r < 8; ++r) {
            int g = w + (r << 4);          // 0..127, wave-uniform
            int row = g & 63;
            if (g < 64) {
                int v = 0;
                if (row < NN && lane < NN) v = A2g[((size_t)b * NN + row) * NN + lane];
                int base = 0, off2 = 0;
                #pragma unroll
                for (int vv = 1; vv <= 4; ++vv) {
                    unsigned long long mv = __ballot(v == vv);
                    if (v == vv)
                        adj2e[row][base + __popcll(mv & lt)] =
                            (unsigned char)(lane | ((vv - 1) << 6));
                    base += __popcll(mv);
                    if (vv == 2) off2 = base;
                }
                if (lane == 0) { adj2n[row] = base; adj2s[row] = off2; }
            } else {
                int v = 0;
                if (row < NN && lane < NN) v = A1g[((size_t)b * NN + row) * NN + lane];
                unsigned long long mk = __ballot(v != 0);
                if (v) adj1e[row][__popcll(mk & lt)] =
                           (unsigned char)(lane | ((v - 1) << 6));
                if (lane == 0) adj1n[row] = __popcll(mk);
            }
        }
    }
    __syncthreads();
    const float eid = ces[6];   // edge ins/del cost
    const float nid = cns[28];  // node ins/del cost

    // ---- phase B: cost tables ----
    if (tid < 64) {
        int r = tid >> 3, c = tid & 7;
        float v = 0.0f;
        if (r != c) {
            int lo = r < c ? r : c, hi = r < c ? c : r;
            v = cns[lo * 7 - (lo * (lo - 1)) / 2 + (hi - lo - 1)];
        }
        ncost[r][c] = v;
    } else if (tid < 80) {
        int a = (tid - 64) >> 2, bb = tid & 3;
        float ec = 0.0f;
        if (a != bb) {
            int lo = a < bb ? a : bb, hi = a < bb ? bb : a;
            ec = ces[lo * 3 - (lo * (lo - 1)) / 2 + (hi - lo - 1)];
        }
        Qs[a][bb] = 2.0f * ec - 2.0f * eid;
    }
    __syncthreads();

    // ---- c matrix in registers + x0 seed ----
    float c_reg[4];
    #pragma unroll
    for (int m = 0; m < 4; ++m) {
        int i = w + (m << 4);
        float cv;
        if (i < NN && lane < NN) cv = ncost[l1s[i]][l2s[lane]];
        else cv = (i == NN && lane == NN) ? 0.0f : nid;
        c_reg[m] = cv;
        Ws[i][lane] = __expf(-cv);
    }
    __syncthreads();

    // ---- sinkhorn: rows <63 row-normalized, then cols <63 col-normalized ----
    const int q  = tid & 15;
    const int rr = tid >> 4;     // 0..63
    const int c0 = q << 2;
    auto sinkhorn = [&](int n_iter) {
        for (int it = 0; it < n_iter; ++it) {
            float s = 0.0f;
            #pragma unroll
            for (int u = 0; u < 4; ++u) s += Ws[rr][c0 + u];
            #pragma unroll
            for (int off = 1; off <= 8; off <<= 1) s += __shfl_xor(s, off, 64);
            if (rr < NN) {
                float inv = __builtin_amdgcn_rcpf(s);
                #pragma unroll
                for (int u = 0; u < 4; ++u) Ws[rr][c0 + u] *= inv;
            }
            __syncthreads();
            s = 0.0f;
            #pragma unroll
            for (int u = 0; u < 4; ++u) s += Ws[c0 + u][rr];
            #pragma unroll
            for (int off = 1; off <= 8; off <<= 1) s += __shfl_xor(s, off, 64);
            if (rr < NN) {
                float inv = __builtin_amdgcn_rcpf(s);
                #pragma unroll
                for (int u = 0; u < 4; ++u) Ws[c0 + u][rr] *= inv;
            }
            __syncthreads();
        }
    };

    // ---- out[m] = (D @ Ws)[i = w+16m, j = lane] ----
    auto matvec = [&](float* out) {
        // phase 1: row sums rX, col sums cXs  +  Y-build pass 0 (labels 1,2)
        {
            float s = 0.0f, s2 = 0.0f;
            #pragma unroll
            for (int u = 0; u < 4; ++u) { s += Ws[rr][c0 + u]; s2 += Ws[c0 + u][rr]; }
            #pragma unroll
            for (int off = 1; off <= 8; off <<= 1) {
                s += __shfl_xor(s, off, 64); s2 += __shfl_xor(s2, off, 64);
            }
            if (q == 0) { rX[rr] = s; cXs[rr] = s2; }
        }
        #pragma unroll
        for (int m = 0; m < 4; ++m) {
            int j = w + (m << 4);
            int e1 = adj2s[j];
            float a0 = 0.0f, a1 = 0.0f;
            for (int e = 0; e < e1; ++e) {
                int p = adj2e[j][e];
                float v = Ws[lane][p & 63];
                a0 += ((p >> 6) == 0) ? v : 0.0f;
                a1 += ((p >> 6) == 1) ? v : 0.0f;
            }
            int kk = lane ^ (j & 31);
            Yt[0][j][kk] = a0;
            Yt[1][j][kk] = a1;
        }
        __syncthreads();
        // phase 2: S1/S2 scans (128 threads) + quadratic pass 0 (all threads)
        if (tid < 64) {
            int j = tid, n = adj2n[j];
            float s = 0.0f;
            for (int e = 0; e < n; ++e) s += cXs[adj2e[j][e] & 63];
            S2s[j] = s;
        } else if (tid < 128) {
            int i = tid - 64, n = adj1n[i];
            float s = 0.0f;
            for (int e = 0; e < n; ++e) s += rX[adj1e[i][e] & 63];
            S1s[i] = s;
        }
        #pragma unroll
        for (int m = 0; m < 4; ++m) {
            int i = w + (m << 4);
            int n = adj1n[i];
            float acc = 0.0f;
            for (int e = 0; e < n; ++e) {
                int p = adj1e[i][e];
                int a = p >> 6, kk = (p & 63) ^ (lane & 31);
                acc += Qs[a][0] * Yt[0][lane][kk] + Qs[a][1] * Yt[1][lane][kk];
            }
            out[m] = acc;
        }
        __syncthreads();
        // phase 3: Y-build pass 1 (labels 3,4) + eid rank-1 term
        #pragma unroll
        for (int m = 0; m < 4; ++m) {
            int j = w + (m << 4);
            int e0 = adj2s[j], e1 = adj2n[j];
            float a0 = 0.0f, a1 = 0.0f;
            for (int e = e0; e < e1; ++e) {
                int p = adj2e[j][e];
                float v = Ws[lane][p & 63];
                a0 += ((p >> 6) == 2) ? v : 0.0f;
                a1 += ((p >> 6) == 3) ? v : 0.0f;
            }
            int kk = lane ^ (j & 31);
            Yt[0][j][kk] = a0;
            Yt[1][j][kk] = a1;
        }
        #pragma unroll
        for (int m = 0; m < 4; ++m)
            out[m] += eid * (S1s[w + (m << 4)] + S2s[lane]);
        __syncthreads();
        // phase 4: quadratic pass 1
        #pragma unroll
        for (int m = 0; m < 4; ++m) {
            int i = w + (m << 4);
            int n = adj1n[i];
            float acc = 0.0f;
            for (int e = 0; e < n; ++e) {
                int p = adj1e[i][e];
                int a = p >> 6, kk = (p & 63) ^ (lane & 31);
                acc += Qs[a][2] * Yt[0][lane][kk] + Qs[a][3] * Yt[1][lane][kk];
            }
            out[m] += acc;
        }
        // no trailing barrier: next Yt/Ws writes are separated by caller barriers
    };

    sinkhorn(10);

    float x[4], dx[4], db[4];
    #pragma unroll
    for (int m = 0; m < 4; ++m) x[m] = Ws[w + (m << 4)][lane];
    matvec(dx);   // dx = D @ x0

    for (int it = 0; it < 15; ++it) {
        // g = c + dx (registers); W = exp(-g)
        #pragma unroll
        for (int m = 0; m < 4; ++m)
            Ws[w + (m << 4)][lane] = __expf(-(c_reg[m] + dx[m]));
        __syncthreads();
        sinkhorn(5);          // Ws := b
        matvec(db);           // db = D @ b
        float dn = 0.0f, nm = 0.0f;
        #pragma unroll
        for (int m = 0; m < 4; ++m) {
            float d = Ws[w + (m << 4)][lane] - x[m];
            dn += d * (db[m] - dx[m]);          // d . (D d)
            nm += d * (c_reg[m] + dx[m]);       // d . g
        }
        #pragma unroll
        for (int off = 32; off >= 1; off >>= 1) {
            dn += __shfl_xor(dn, off, 64);
            nm += __shfl_xor(nm, off, 64);
        }
        if (lane == 0) { red[w] = dn; red[16 + w] = nm; }
        __syncthreads();
        if (tid == 0) {
            float den = 0.0f, num = 0.0f;
            #pragma unroll
            for (int u = 0; u < 16; ++u) { den += red[u]; num += red[16 + u]; }
            float t;
            if (den > 0.0f) t = fminf(fmaxf(-num / den, 0.0f), 1.0f);
            else            t = (num < 0.0f) ? 1.0f : 0.0f;
            tshare = t;
        }
        __syncthreads();
        float t = tshare;
        #pragma unroll
        for (int m = 0; m < 4; ++m) {
            float d = Ws[w + (m << 4)][lane] - x[m];
            x[m]  += t * d;
            dx[m] += t * (db[m] - dx[m]);   // D x_new tracked by linearity
        }
        // no barrier needed: remaining Ws accesses are owner-local until next exp+barrier
    }

    // ged = 0.5 * x.Dx + c.x
    float g = 0.0f;
    #pragma unroll
    for (int m = 0; m < 4; ++m) g += x[m] * (0.5f * dx[m] + c_reg[m]);
    #pragma unroll
    for (int off = 32; off >= 1; off >>= 1) g += __shfl_xor(g, off, 64);
    if (lane == 0) red[w] = g;
    __syncthreads();
    if (tid == 0) {
        float s = 0.0f;
        #pragma unroll
        for (int u = 0; u < 16; ++u) s += red[u];
        ged_out[b] = s;
    }
}

__global__ void norm_kernel(const float* __restrict__ g, float* __restrict__ out) {
    int t = threadIdx.x;
    if (t < NBATCH) {
        float mn = g[0], mx = g[0];
        #pragma unroll
        for (int i = 1; i < NBATCH; ++i) { mn = fminf(mn, g[i]); mx = fmaxf(mx, g[i]); }
        out[t] = (g[t] - mn) / (mx - mn);
    }
}

extern "C" void kernel_launch(void* const* d_in, const int* in_sizes, int n_in,
                              void* d_out, int out_size, void* d_ws, size_t ws_size,
                              hipStream_t stream) {
    (void)in_sizes; (void)n_in; (void)out_size; (void)ws_size;
    const float* node_w = (const float*)d_in[0];
    const float* edge_w = (const float*)d_in[1];
    const int*   A1     = (const int*)d_in[2];
    const int*   A2     = (const int*)d_in[3];
    const int*   l1     = (const int*)d_in[4];
    const int*   l2     = (const int*)d_in[5];
    float* ged = (float*)d_ws;
    ged_kernel<<<dim3(NBATCH), dim3(1024), 0, stream>>>(node_w, edge_w, A1, A2, l1, l2, ged);
    norm_kernel<<<dim3(1), dim3(64), 0, stream>>>(ged, (float*)d_out);
}

// Round 4
// 235.163 us; speedup vs baseline: 3.8698x; 1.1717x over previous
//
#include <hip/hip_runtime.h>
#include <math.h>

#define NBATCH 16
#define NN 63

// One block per batch element. 1024 threads = 16 waves.
// FW/elementwise mapping: w = tid>>6, lane = tid&63 (= column j), rows i = w + 16m, m=0..3.
// Sinkhorn mapping: rr = tid>>4 (row), q = tid&15, cols c0..c0+3 (c0 = 4q).
__global__ __launch_bounds__(1024) void ged_kernel(
    const float* __restrict__ node_w, const float* __restrict__ edge_w,
    const int* __restrict__ A1g, const int* __restrict__ A2g,
    const int* __restrict__ l1g, const int* __restrict__ l2g,
    float* __restrict__ ged_out)
{
    const int b    = blockIdx.x;
    const int tid  = threadIdx.x;
    const int lane = tid & 63;
    const int w    = tid >> 6;

    __shared__ __align__(16) float XK[64*65];     // K then X workspace, [row*65+col]
    __shared__ __align__(16) float Zt[2][64*64];  // Z planes, [k*64 + (j ^ (k&31))]
    __shared__ __align__(16) float us[64];
    __shared__ __align__(16) float vs[64];
    __shared__ float rX[64], cXs[64], S1s[64], S2s[64];
    __shared__ float red[32];
    __shared__ float ncost[64];
    __shared__ float Qs[16];                      // Q[a*4+b] = 2*ec[a][b] - 2*eid
    __shared__ float cns[29], ces[7];
    __shared__ int   l1s[64], l2s[64];
    __shared__ int   adj1o[64*5], adj2o[64*5];    // label-section offsets, o[4]=n
    __shared__ unsigned char adj1e[64*64], adj2e[64*64];  // label-sorted neighbor ids

    // ---- S0a: weights, labels, adjacency (ballot-sorted by label) ----
    if (tid < 29) cns[tid] = fmaxf(node_w[tid], 0.f);
    else if (tid >= 32 && tid < 39) ces[tid-32] = fmaxf(edge_w[tid-32], 0.f);
    if (tid >= 256 && tid < 320) l1s[tid-256] = (tid-256 < NN) ? l1g[b*NN + tid-256] : 0;
    else if (tid >= 320 && tid < 384) l2s[tid-320] = (tid-320 < NN) ? l2g[b*NN + tid-320] : 0;
    {
        const unsigned long long lt = (1ull << lane) - 1ull;
        #pragma unroll
        for (int r = 0; r < 8; ++r) {
            int g = (w << 3) + r;            // 0..127, wave-uniform
            int row = g & 63;
            const int* src = (g < 64) ? A2g : A1g;
            unsigned char* dst = (g < 64) ? adj2e : adj1e;
            int* odst = (g < 64) ? adj2o : adj1o;
            int v = 0;
            if (row < NN && lane < NN) v = src[((size_t)b * NN + row) * NN + lane];
            int base = 0;
            #pragma unroll
            for (int vv = 1; vv <= 4; ++vv) {
                if (lane == 0) odst[row*5 + vv-1] = base;
                unsigned long long mv = __ballot(v == vv);
                if (v == vv) dst[(row<<6) + base + __popcll(mv & lt)] = (unsigned char)lane;
                base += __popcll(mv);
            }
            if (lane == 0) odst[row*5 + 4] = base;
        }
    }
    __syncthreads();
    const float eid = ces[6];
    const float nid = cns[28];

    // ---- S0b: cost tables ----
    if (tid < 64) {
        int r0 = tid >> 3, c1 = tid & 7;
        float vv = 0.f;
        if (r0 != c1) {
            int lo = min(r0, c1), hi = max(r0, c1);
            vv = cns[lo*7 - (lo*(lo-1))/2 + (hi-lo-1)];
        }
        ncost[tid] = vv;
    } else if (tid < 80) {
        int a = (tid-64) >> 2, b2 = tid & 3;
        float ec = 0.f;
        if (a != b2) {
            int lo = min(a, b2), hi = max(a, b2);
            ec = ces[lo*3 - (lo*(lo-1))/2 + (hi-lo-1)];
        }
        Qs[tid-64] = 2.f*ec - 2.f*eid;
    }
    __syncthreads();

    float Qreg[16];
    #pragma unroll
    for (int u2 = 0; u2 < 16; ++u2) Qreg[u2] = Qs[u2];

    // ---- c matrix in registers + K0 = exp(-c) ----
    float c_reg[4];
    #pragma unroll
    for (int m = 0; m < 4; ++m) {
        int i = w + (m << 4);
        float cv;
        if (i < NN && lane < NN) cv = ncost[(l1s[i] << 3) + l2s[lane]];
        else cv = (i == NN && lane == NN) ? 0.f : nid;
        c_reg[m] = cv;
        XK[i*65 + lane] = __expf(-cv);
    }
    __syncthreads();

    const int q  = tid & 15;
    const int rr = tid >> 4;
    const int c0 = q << 2;
    float Krow[4], Kcol[4];

    auto grp_reduce = [&](float s) {
        s += __shfl_xor(s, 1, 64);
        s += __shfl_xor(s, 2, 64);
        s += __shfl_xor(s, 4, 64);
        s += __shfl_xor(s, 8, 64);
        return s;
    };

    // scaling-vector sinkhorn: u = 1/(Kv) (inner rows), v = 1/(u^T K) (inner cols)
    auto sinkhorn = [&](int iters) {
        #pragma unroll
        for (int u = 0; u < 4; ++u) {
            Krow[u] = XK[rr*65 + c0 + u];
            Kcol[u] = XK[(c0+u)*65 + rr];
        }
        float s = grp_reduce(Krow[0] + Krow[1] + Krow[2] + Krow[3]);  // v0 = 1
        if (q == 0) us[rr] = (rr < NN) ? __builtin_amdgcn_rcpf(s) : 1.f;
        __syncthreads();
        for (int it = 0; it < iters; ++it) {
            {
                float4 u4 = *(const float4*)&us[c0];
                float t = grp_reduce(Kcol[0]*u4.x + Kcol[1]*u4.y + Kcol[2]*u4.z + Kcol[3]*u4.w);
                if (q == 0) vs[rr] = (rr < NN) ? __builtin_amdgcn_rcpf(t) : 1.f;
                __syncthreads();
            }
            if (it + 1 < iters) {
                float4 v4 = *(const float4*)&vs[c0];
                float t = grp_reduce(Krow[0]*v4.x + Krow[1]*v4.y + Krow[2]*v4.z + Krow[3]*v4.w);
                if (q == 0) us[rr] = (rr < NN) ? __builtin_amdgcn_rcpf(t) : 1.f;
                __syncthreads();
            }
        }
    };

    // materialize X = u*K*v into XK + row/col sums
    auto finalize = [&]() {
        float4 v4 = *(const float4*)&vs[c0];
        float4 u4 = *(const float4*)&us[c0];
        float uR = us[rr], vR = vs[rr];
        float sr = grp_reduce(Krow[0]*v4.x + Krow[1]*v4.y + Krow[2]*v4.z + Krow[3]*v4.w);
        float sc = grp_reduce(Kcol[0]*u4.x + Kcol[1]*u4.y + Kcol[2]*u4.z + Kcol[3]*u4.w);
        if (q == 0) { rX[rr] = uR * sr; cXs[rr] = vR * sc; }
        XK[rr*65 + c0 + 0] = uR * Krow[0] * v4.x;
        XK[rr*65 + c0 + 1] = uR * Krow[1] * v4.y;
        XK[rr*65 + c0 + 2] = uR * Krow[2] * v4.z;
        XK[rr*65 + c0 + 3] = uR * Krow[3] * v4.w;
        __syncthreads();
    };

    float accY[4][4];  // Y[b][j][k=lane] for this thread's 4 rows j, kept across Z passes

    // P: S-scans (8 threads/row) + Y-accumulate (sections) + write Z planes a=0,1
    auto buildYZ0_S = [&]() {
        {
            int row8 = tid >> 3, sub = tid & 7;
            int row = row8 & 63;
            const unsigned char* ae = (row8 < 64) ? &adj2e[row<<6] : &adj1e[row<<6];
            int n = (row8 < 64) ? adj2o[row*5+4] : adj1o[row*5+4];
            const float* vsum = (row8 < 64) ? cXs : rX;
            float s = 0.f;
            for (int e = sub; e < n; e += 8) s += vsum[ae[e]];
            s += __shfl_xor(s, 1, 64);
            s += __shfl_xor(s, 2, 64);
            s += __shfl_xor(s, 4, 64);
            if (sub == 0) { if (row8 < 64) S2s[row] = s; else S1s[row] = s; }
        }
        const int xb = lane * 65;
        #pragma unroll
        for (int m = 0; m < 4; ++m) {
            int j = w + (m << 4);
            const unsigned char* ae = &adj2e[j<<6];
            const int* o = &adj2o[j*5];
            #pragma unroll
            for (int bb2 = 0; bb2 < 4; ++bb2) {
                float a = 0.f;
                int e0 = o[bb2], e1 = o[bb2+1];
                for (int e = e0; e < e1; ++e) {
                    int l = __builtin_amdgcn_readfirstlane((int)ae[e]);
                    a += XK[xb + l];
                }
                accY[m][bb2] = a;
            }
            int zi = (lane << 6) + (j ^ (lane & 31));
            Zt[0][zi] = Qreg[0]*accY[m][0] + Qreg[1]*accY[m][1] + Qreg[2]*accY[m][2] + Qreg[3]*accY[m][3];
            Zt[1][zi] = Qreg[4]*accY[m][0] + Qreg[5]*accY[m][1] + Qreg[6]*accY[m][2] + Qreg[7]*accY[m][3];
        }
        __syncthreads();
    };

    auto writeZ1 = [&]() {
        #pragma unroll
        for (int m = 0; m < 4; ++m) {
            int j = w + (m << 4);
            int zi = (lane << 6) + (j ^ (lane & 31));
            Zt[0][zi] = Qreg[8]*accY[m][0]  + Qreg[9]*accY[m][1]  + Qreg[10]*accY[m][2] + Qreg[11]*accY[m][3];
            Zt[1][zi] = Qreg[12]*accY[m][0] + Qreg[13]*accY[m][1] + Qreg[14]*accY[m][2] + Qreg[15]*accY[m][3];
        }
        __syncthreads();
    };

    auto quad_pass = [&](int pass, float* db) {
        #pragma unroll
        for (int m = 0; m < 4; ++m) {
            int i = w + (m << 4);
            const unsigned char* ae = &adj1e[i<<6];
            const int* o = &adj1o[i*5];
            float acc = 0.f;
            #pragma unroll
            for (int aa = 0; aa < 2; ++aa) {
                int a = (pass << 1) + aa;
                int e0 = o[a], e1 = o[a+1];
                const float* zp = Zt[aa];
                for (int e = e0; e < e1; ++e) {
                    int k = __builtin_amdgcn_readfirstlane((int)ae[e]);
                    acc += zp[(k << 6) + (lane ^ (k & 31))];
                }
            }
            db[m] += acc;
        }
    };

    // ---- init: x0 = sinkhorn(exp(-c), 10); dx = D @ x0 ----
    sinkhorn(10);
    finalize();
    buildYZ0_S();
    float x[4], dx[4], bb4[4];
    #pragma unroll
    for (int m = 0; m < 4; ++m) dx[m] = eid * (S1s[w + (m<<4)] + S2s[lane]);
    quad_pass(0, dx);
    #pragma unroll
    for (int m = 0; m < 4; ++m) x[m] = XK[(w + (m<<4))*65 + lane];
    __syncthreads();
    writeZ1();
    quad_pass(1, dx);

    // ---- Frank-Wolfe iterations ----
    for (int it = 0; it < 15; ++it) {
        // P0: K = exp(-(c + dx))   (all prior XK/Zt readers are barrier-separated)
        __syncthreads();
        #pragma unroll
        for (int m = 0; m < 4; ++m)
            XK[(w + (m<<4))*65 + lane] = __expf(-(c_reg[m] + dx[m]));
        __syncthreads();
        sinkhorn(5);
        finalize();
        buildYZ0_S();
        float db[4];
        #pragma unroll
        for (int m = 0; m < 4; ++m) db[m] = eid * (S1s[w + (m<<4)] + S2s[lane]);
        quad_pass(0, db);
        #pragma unroll
        for (int m = 0; m < 4; ++m) bb4[m] = XK[(w + (m<<4))*65 + lane];
        __syncthreads();
        writeZ1();
        quad_pass(1, db);
        // dn = d.(Db - Dx), nm = d.g
        float dn = 0.f, nm = 0.f;
        #pragma unroll
        for (int m = 0; m < 4; ++m) {
            float d = bb4[m] - x[m];
            dn += d * (db[m] - dx[m]);
            nm += d * (c_reg[m] + dx[m]);
        }
        #pragma unroll
        for (int off = 32; off >= 1; off >>= 1) {
            dn += __shfl_xor(dn, off, 64);
            nm += __shfl_xor(nm, off, 64);
        }
        if (lane == 0) { red[w] = dn; red[16 + w] = nm; }
        __syncthreads();
        float den = 0.f, num = 0.f;
        #pragma unroll
        for (int u = 0; u < 16; ++u) { den += red[u]; num += red[16 + u]; }
        float t;
        if (den > 0.f) t = fminf(fmaxf(-num / den, 0.f), 1.f);
        else           t = (num < 0.f) ? 1.f : 0.f;
        #pragma unroll
        for (int m = 0; m < 4; ++m) {
            float d = bb4[m] - x[m];
            x[m]  += t * d;
            dx[m] += t * (db[m] - dx[m]);   // D x_new tracked by linearity
        }
        // no trailing barrier: next P0 has its own leading barrier
    }

    // ---- ged = 0.5 * x.Dx + c.x ----
    __syncthreads();   // protect red[] (still being read above) before rewrite
    float g2 = 0.f;
    #pragma unroll
    for (int m = 0; m < 4; ++m) g2 += x[m] * (0.5f * dx[m] + c_reg[m]);
    #pragma unroll
    for (int off = 32; off >= 1; off >>= 1) g2 += __shfl_xor(g2, off, 64);
    if (lane == 0) red[w] = g2;
    __syncthreads();
    if (tid == 0) {
        float s = 0.f;
        #pragma unroll
        for (int u = 0; u < 16; ++u) s += red[u];
        ged_out[b] = s;
    }
}

__global__ void norm_kernel(const float* __restrict__ g, float* __restrict__ out) {
    int t = threadIdx.x;
    if (t < NBATCH) {
        float mn = g[0], mx = g[0];
        #pragma unroll
        for (int i = 1; i < NBATCH; ++i) { mn = fminf(mn, g[i]); mx = fmaxf(mx, g[i]); }
        out[t] = (g[t] - mn) / (mx - mn);
    }
}

extern "C" void kernel_launch(void* const* d_in, const int* in_sizes, int n_in,
                              void* d_out, int out_size, void* d_ws, size_t ws_size,
                              hipStream_t stream) {
    (void)in_sizes; (void)n_in; (void)out_size; (void)ws_size;
    const float* node_w = (const float*)d_in[0];
    const float* edge_w = (const float*)d_in[1];
    const int*   A1     = (const int*)d_in[2];
    const int*   A2     = (const int*)d_in[3];
    const int*   l1     = (const int*)d_in[4];
    const int*   l2     = (const int*)d_in[5];
    float* ged = (float*)d_ws;
    ged_kernel<<<dim3(NBATCH), dim3(1024), 0, stream>>>(node_w, edge_w, A1, A2, l1, l2, ged);
    norm_kernel<<<dim3(1), dim3(64), 0, stream>>>(ged, (float*)d_out);
}

// Round 5
// 190.089 us; speedup vs baseline: 4.7875x; 1.2371x over previous
//
#include <hip/hip_runtime.h>
#include <math.h>

#define NBATCH 16
#define NN 63

// One block per batch element. 1024 threads = 16 waves.
// FW/elementwise mapping: w = tid>>6, lane = tid&63 (= column j), rows i = w + 16m, m=0..3.
// Sinkhorn mapping: rr = tid>>4 (row), q = tid&15, cols c0..c0+3 (c0 = 4q).
// Adjacency: per row, label-sorted edge list, each label section padded to a
// 4-byte word boundary with null index 64. All gather targets have a zero
// slot at index 64 (XK col 64, Zt row 64, rX/cXs[64]).
__global__ __launch_bounds__(1024) void ged_kernel(
    const float* __restrict__ node_w, const float* __restrict__ edge_w,
    const int* __restrict__ A1g, const int* __restrict__ A2g,
    const int* __restrict__ l1g, const int* __restrict__ l2g,
    float* __restrict__ ged_out)
{
    const int b    = blockIdx.x;
    const int tid  = threadIdx.x;
    const int lane = tid & 63;
    const int w    = tid >> 6;

    __shared__ __align__(16) float XK[64*65];     // K then X, [row*65+col]; col 64 = 0
    __shared__ __align__(16) float Zt[2][65*65];  // Z planes, [k*65+j]; row 64 = 0
    __shared__ __align__(16) float us[64];
    __shared__ __align__(16) float vs[64];
    __shared__ float rX[65], cXs[65];             // [64] = 0
    __shared__ float S1s[64], S2s[64];
    __shared__ __align__(16) float red[32];
    __shared__ float ncost[64];
    __shared__ float Qs[16];                      // Q[a*4+b] = 2*ec[a][b] - 2*eid
    __shared__ float cns[29], ces[7];
    __shared__ int   l1s[64], l2s[64];
    __shared__ __align__(4) unsigned char adjo1[64*8], adjo2[64*8]; // byte offsets o0..o4 (word-aligned values)
    __shared__ __align__(4) unsigned char adj1e[64*80], adj2e[64*80];

    // ---- S0: prefill + small loads ----
    for (int t2 = tid; t2 < 1280; t2 += 1024) {
        ((unsigned int*)adj1e)[t2] = 0x40404040u;
        ((unsigned int*)adj2e)[t2] = 0x40404040u;
    }
    if (tid < 29) cns[tid] = fmaxf(node_w[tid], 0.f);
    else if (tid >= 32 && tid < 39) ces[tid-32] = fmaxf(edge_w[tid-32], 0.f);
    if (tid >= 64 && tid < 128) XK[(tid-64)*65 + 64] = 0.f;
    else if (tid >= 128 && tid < 193) Zt[0][64*65 + (tid-128)] = 0.f;
    else if (tid >= 193 && tid < 258) Zt[1][64*65 + (tid-193)] = 0.f;
    if (tid == 40) { rX[64] = 0.f; cXs[64] = 0.f; }
    if (tid >= 320 && tid < 384) l1s[tid-320] = (tid-320 < NN) ? l1g[b*NN + tid-320] : 0;
    else if (tid >= 384 && tid < 448) l2s[tid-384] = (tid-384 < NN) ? l2g[b*NN + tid-384] : 0;
    __syncthreads();

    // ---- S1: ballot adjacency build (label-sorted, word-padded) + cost tables ----
    {
        const unsigned long long lt = (1ull << lane) - 1ull;
        #pragma unroll
        for (int r = 0; r < 8; ++r) {
            int g = (w << 3) + r;            // 0..127, wave-uniform
            int row = g & 63;
            const int* src = (g < 64) ? A2g : A1g;
            unsigned char* dst = (g < 64) ? adj2e : adj1e;
            unsigned char* odst = (g < 64) ? adjo2 : adjo1;
            int v = 0;
            if (row < NN && lane < NN) v = src[((size_t)b * NN + row) * NN + lane];
            int base = 0;
            #pragma unroll
            for (int vv = 1; vv <= 4; ++vv) {
                if (lane == 0) odst[row*8 + vv-1] = (unsigned char)base;
                unsigned long long mv = __ballot(v == vv);
                if (v == vv) dst[row*80 + base + __popcll(mv & lt)] = (unsigned char)lane;
                base += __popcll(mv);
                base = (base + 3) & ~3;      // word-align next section
            }
            if (lane == 0) odst[row*8 + 4] = (unsigned char)base;
        }
    }
    if (tid < 64) {
        int r0 = tid >> 3, c1 = tid & 7;
        float vv = 0.f;
        if (r0 != c1) {
            int lo = min(r0, c1), hi = max(r0, c1);
            vv = cns[lo*7 - (lo*(lo-1))/2 + (hi-lo-1)];
        }
        ncost[tid] = vv;
    } else if (tid < 80) {
        int a = (tid-64) >> 2, b2 = tid & 3;
        float ec = 0.f;
        if (a != b2) {
            int lo = min(a, b2), hi = max(a, b2);
            ec = ces[lo*3 - (lo*(lo-1))/2 + (hi-lo-1)];
        }
        Qs[tid-64] = 2.f*ec - 2.f*ces[6];
    }
    __syncthreads();
    const float eid = ces[6];
    const float nid = cns[28];

    float Qreg[16];
    #pragma unroll
    for (int u2 = 0; u2 < 16; ++u2) Qreg[u2] = Qs[u2];

    // ---- c matrix in registers + K0 = exp(-c) ----
    float c_reg[4];
    #pragma unroll
    for (int m = 0; m < 4; ++m) {
        int i = w + (m << 4);
        float cv;
        if (i < NN && lane < NN) cv = ncost[(l1s[i] << 3) + l2s[lane]];
        else cv = (i == NN && lane == NN) ? 0.f : nid;
        c_reg[m] = cv;
        XK[i*65 + lane] = __expf(-cv);
    }
    __syncthreads();

    const int q  = tid & 15;
    const int rr = tid >> 4;
    const int c0 = q << 2;
    float Krow[4], Kcol[4];

    auto grp_reduce = [&](float s) {
        s += __shfl_xor(s, 1, 64);
        s += __shfl_xor(s, 2, 64);
        s += __shfl_xor(s, 4, 64);
        s += __shfl_xor(s, 8, 64);
        return s;
    };

    // scaling-vector sinkhorn: u = 1/(Kv) (inner rows), v = 1/(u^T K) (inner cols)
    auto sinkhorn = [&](int iters) {
        #pragma unroll
        for (int u = 0; u < 4; ++u) {
            Krow[u] = XK[rr*65 + c0 + u];
            Kcol[u] = XK[(c0+u)*65 + rr];
        }
        float s = grp_reduce(Krow[0] + Krow[1] + Krow[2] + Krow[3]);  // v0 = 1
        if (q == 0) us[rr] = (rr < NN) ? __builtin_amdgcn_rcpf(s) : 1.f;
        __syncthreads();
        for (int it = 0; it < iters; ++it) {
            {
                float4 u4 = *(const float4*)&us[c0];
                float t = grp_reduce(Kcol[0]*u4.x + Kcol[1]*u4.y + Kcol[2]*u4.z + Kcol[3]*u4.w);
                if (q == 0) vs[rr] = (rr < NN) ? __builtin_amdgcn_rcpf(t) : 1.f;
                __syncthreads();
            }
            if (it + 1 < iters) {
                float4 v4 = *(const float4*)&vs[c0];
                float t = grp_reduce(Krow[0]*v4.x + Krow[1]*v4.y + Krow[2]*v4.z + Krow[3]*v4.w);
                if (q == 0) us[rr] = (rr < NN) ? __builtin_amdgcn_rcpf(t) : 1.f;
                __syncthreads();
            }
        }
    };

    // materialize X = u*K*v into XK + row/col sums
    auto finalize = [&]() {
        float4 v4 = *(const float4*)&vs[c0];
        float4 u4 = *(const float4*)&us[c0];
        float uR = us[rr], vR = vs[rr];
        float sr = grp_reduce(Krow[0]*v4.x + Krow[1]*v4.y + Krow[2]*v4.z + Krow[3]*v4.w);
        float sc = grp_reduce(Kcol[0]*u4.x + Kcol[1]*u4.y + Kcol[2]*u4.z + Kcol[3]*u4.w);
        if (q == 0) { rX[rr] = uR * sr; cXs[rr] = vR * sc; }
        XK[rr*65 + c0 + 0] = uR * Krow[0] * v4.x;
        XK[rr*65 + c0 + 1] = uR * Krow[1] * v4.y;
        XK[rr*65 + c0 + 2] = uR * Krow[2] * v4.z;
        XK[rr*65 + c0 + 3] = uR * Krow[3] * v4.w;
        __syncthreads();
    };

    float accY[4][4];  // per-section Y sums for this thread's 4 rows j, k=lane

    // S-scans (8 threads/row, word loop) + Y-accumulate (word loop) + write Z planes a=0,1
    auto buildYZ0_S = [&]() {
        {
            int row8 = tid >> 3, sub = tid & 7;
            int row = row8 & 63;
            const unsigned int* wp;
            const float* vsum;
            int nby;
            if (row8 < 64) { wp = (const unsigned int*)&adj2e[row*80]; nby = adjo2[row*8+4]; vsum = cXs; }
            else           { wp = (const unsigned int*)&adj1e[row*80]; nby = adjo1[row*8+4]; vsum = rX; }
            int nw = nby >> 2;
            float s = 0.f;
            for (int ww = sub; ww < nw; ww += 8) {
                unsigned int wd = wp[ww];
                s += vsum[wd & 0x7f] + vsum[(wd>>8) & 0x7f]
                   + vsum[(wd>>16) & 0x7f] + vsum[(wd>>24) & 0x7f];
            }
            s += __shfl_xor(s, 1, 64);
            s += __shfl_xor(s, 2, 64);
            s += __shfl_xor(s, 4, 64);
            if (sub == 0) { if (row8 < 64) S2s[row] = s; else S1s[row] = s; }
        }
        const int xb = lane * 65;
        #pragma unroll
        for (int m = 0; m < 4; ++m) {
            int j = w + (m << 4);
            const unsigned int* wp = (const unsigned int*)&adj2e[j*80];
            unsigned int ow0 = ((const unsigned int*)adjo2)[j*2];
            unsigned int ow1 = ((const unsigned int*)adjo2)[j*2+1];
            int w0 = (ow0 & 255) >> 2, w1 = ((ow0>>8) & 255) >> 2;
            int w2 = ((ow0>>16) & 255) >> 2, w3 = (ow0 >> 24) >> 2;
            int w4 = (ow1 & 255) >> 2;
            float a0 = 0.f, a1 = 0.f, a2 = 0.f, a3 = 0.f;
            for (int ww = w0; ww < w1; ++ww) {
                unsigned int wd = wp[ww];
                a0 += XK[xb + (wd & 0x7f)] + XK[xb + ((wd>>8) & 0x7f)]
                    + XK[xb + ((wd>>16) & 0x7f)] + XK[xb + ((wd>>24) & 0x7f)];
            }
            for (int ww = w1; ww < w2; ++ww) {
                unsigned int wd = wp[ww];
                a1 += XK[xb + (wd & 0x7f)] + XK[xb + ((wd>>8) & 0x7f)]
                    + XK[xb + ((wd>>16) & 0x7f)] + XK[xb + ((wd>>24) & 0x7f)];
            }
            for (int ww = w2; ww < w3; ++ww) {
                unsigned int wd = wp[ww];
                a2 += XK[xb + (wd & 0x7f)] + XK[xb + ((wd>>8) & 0x7f)]
                    + XK[xb + ((wd>>16) & 0x7f)] + XK[xb + ((wd>>24) & 0x7f)];
            }
            for (int ww = w3; ww < w4; ++ww) {
                unsigned int wd = wp[ww];
                a3 += XK[xb + (wd & 0x7f)] + XK[xb + ((wd>>8) & 0x7f)]
                    + XK[xb + ((wd>>16) & 0x7f)] + XK[xb + ((wd>>24) & 0x7f)];
            }
            accY[m][0] = a0; accY[m][1] = a1; accY[m][2] = a2; accY[m][3] = a3;
            int zi = xb + j;   // [k=lane][j]
            Zt[0][zi] = Qreg[0]*a0 + Qreg[1]*a1 + Qreg[2]*a2 + Qreg[3]*a3;
            Zt[1][zi] = Qreg[4]*a0 + Qreg[5]*a1 + Qreg[6]*a2 + Qreg[7]*a3;
        }
        __syncthreads();
    };

    auto writeZ1 = [&]() {
        #pragma unroll
        for (int m = 0; m < 4; ++m) {
            int j = w + (m << 4);
            int zi = lane*65 + j;
            Zt[0][zi] = Qreg[8]*accY[m][0]  + Qreg[9]*accY[m][1]  + Qreg[10]*accY[m][2] + Qreg[11]*accY[m][3];
            Zt[1][zi] = Qreg[12]*accY[m][0] + Qreg[13]*accY[m][1] + Qreg[14]*accY[m][2] + Qreg[15]*accY[m][3];
        }
        __syncthreads();
    };

    // quad: acc4[m] += sum over adj1 sections (2 per pass) of Z[plane][k][lane]
    auto quad_pass = [&](int pass, float* acc4) {
        #pragma unroll
        for (int m = 0; m < 4; ++m) {
            int i = w + (m << 4);
            const unsigned int* wp = (const unsigned int*)&adj1e[i*80];
            unsigned int ow0 = ((const unsigned int*)adjo1)[i*2];
            unsigned int ow1 = ((const unsigned int*)adjo1)[i*2+1];
            int oA, oB, oC;
            if (pass == 0) {
                oA = (ow0 & 255) >> 2; oB = ((ow0>>8) & 255) >> 2; oC = ((ow0>>16) & 255) >> 2;
            } else {
                oA = ((ow0>>16) & 255) >> 2; oB = (ow0 >> 24) >> 2; oC = (ow1 & 255) >> 2;
            }
            float acc = 0.f;
            for (int ww = oA; ww < oB; ++ww) {
                unsigned int wd = wp[ww];
                acc += Zt[0][(wd & 0x7f)*65 + lane] + Zt[0][((wd>>8) & 0x7f)*65 + lane]
                     + Zt[0][((wd>>16) & 0x7f)*65 + lane] + Zt[0][((wd>>24) & 0x7f)*65 + lane];
            }
            for (int ww = oB; ww < oC; ++ww) {
                unsigned int wd = wp[ww];
                acc += Zt[1][(wd & 0x7f)*65 + lane] + Zt[1][((wd>>8) & 0x7f)*65 + lane]
                     + Zt[1][((wd>>16) & 0x7f)*65 + lane] + Zt[1][((wd>>24) & 0x7f)*65 + lane];
            }
            acc4[m] += acc;
        }
    };

    // ---- init: x0 = sinkhorn(exp(-c), 10); dx = D @ x0 ----
    sinkhorn(10);
    finalize();
    buildYZ0_S();
    float x[4], dx[4], bb4[4];
    #pragma unroll
    for (int m = 0; m < 4; ++m) dx[m] = eid * (S1s[w + (m<<4)] + S2s[lane]);
    quad_pass(0, dx);
    #pragma unroll
    for (int m = 0; m < 4; ++m) x[m] = XK[(w + (m<<4))*65 + lane];
    __syncthreads();
    writeZ1();
    quad_pass(1, dx);

    // ---- Frank-Wolfe iterations ----
    for (int it = 0; it < 15; ++it) {
        // P0: K = exp(-(c + dx)); no leading barrier needed (no cross-wave XK/Zt
        // readers remain past the red barrier of the previous iteration)
        #pragma unroll
        for (int m = 0; m < 4; ++m)
            XK[(w + (m<<4))*65 + lane] = __expf(-(c_reg[m] + dx[m]));
        __syncthreads();
        sinkhorn(5);
        finalize();
        buildYZ0_S();
        float db[4];
        #pragma unroll
        for (int m = 0; m < 4; ++m) db[m] = eid * (S1s[w + (m<<4)] + S2s[lane]);
        quad_pass(0, db);
        #pragma unroll
        for (int m = 0; m < 4; ++m) bb4[m] = XK[(w + (m<<4))*65 + lane];
        __syncthreads();
        writeZ1();
        quad_pass(1, db);
        // dn = d.(Db - Dx), nm = d.g
        float dn = 0.f, nm = 0.f;
        #pragma unroll
        for (int m = 0; m < 4; ++m) {
            float d = bb4[m] - x[m];
            dn += d * (db[m] - dx[m]);
            nm += d * (c_reg[m] + dx[m]);
        }
        #pragma unroll
        for (int off = 32; off >= 1; off >>= 1) {
            dn += __shfl_xor(dn, off, 64);
            nm += __shfl_xor(nm, off, 64);
        }
        if (lane == 0) { red[w] = dn; red[16 + w] = nm; }
        __syncthreads();
        const float4* r4 = (const float4*)red;
        float4 p0 = r4[0], p1 = r4[1], p2 = r4[2], p3 = r4[3];
        float4 p4 = r4[4], p5 = r4[5], p6 = r4[6], p7 = r4[7];
        float den = (p0.x+p0.y+p0.z+p0.w) + (p1.x+p1.y+p1.z+p1.w)
                  + (p2.x+p2.y+p2.z+p2.w) + (p3.x+p3.y+p3.z+p3.w);
        float num = (p4.x+p4.y+p4.z+p4.w) + (p5.x+p5.y+p5.z+p5.w)
                  + (p6.x+p6.y+p6.z+p6.w) + (p7.x+p7.y+p7.z+p7.w);
        float t;
        if (den > 0.f) t = fminf(fmaxf(-num / den, 0.f), 1.f);
        else           t = (num < 0.f) ? 1.f : 0.f;
        #pragma unroll
        for (int m = 0; m < 4; ++m) {
            float d = bb4[m] - x[m];
            x[m]  += t * d;
            dx[m] += t * (db[m] - dx[m]);   // D x_new tracked by linearity
        }
    }

    // ---- ged = 0.5 * x.Dx + c.x ----
    __syncthreads();   // red[] still being read above by other waves
    float g2 = 0.f;
    #pragma unroll
    for (int m = 0; m < 4; ++m) g2 += x[m] * (0.5f * dx[m] + c_reg[m]);
    #pragma unroll
    for (int off = 32; off >= 1; off >>= 1) g2 += __shfl_xor(g2, off, 64);
    if (lane == 0) red[w] = g2;
    __syncthreads();
    if (tid == 0) {
        float s = 0.f;
        #pragma unroll
        for (int u = 0; u < 16; ++u) s += red[u];
        ged_out[b] = s;
    }
}

__global__ void norm_kernel(const float* __restrict__ g, float* __restrict__ out) {
    int t = threadIdx.x;
    if (t < NBATCH) {
        float mn = g[0], mx = g[0];
        #pragma unroll
        for (int i = 1; i < NBATCH; ++i) { mn = fminf(mn, g[i]); mx = fmaxf(mx, g[i]); }
        out[t] = (g[t] - mn) / (mx - mn);
    }
}

extern "C" void kernel_launch(void* const* d_in, const int* in_sizes, int n_in,
                              void* d_out, int out_size, void* d_ws, size_t ws_size,
                              hipStream_t stream) {
    (void)in_sizes; (void)n_in; (void)out_size; (void)ws_size;
    const float* node_w = (const float*)d_in[0];
    const float* edge_w = (const float*)d_in[1];
    const int*   A1     = (const int*)d_in[2];
    const int*   A2     = (const int*)d_in[3];
    const int*   l1     = (const int*)d_in[4];
    const int*   l2     = (const int*)d_in[5];
    float* ged = (float*)d_ws;
    ged_kernel<<<dim3(NBATCH), dim3(1024), 0, stream>>>(node_w, edge_w, A1, A2, l1, l2, ged);
    norm_kernel<<<dim3(1), dim3(64), 0, stream>>>(ged, (float*)d_out);
}

// Round 6
// 183.088 us; speedup vs baseline: 4.9705x; 1.0382x over previous
//
#include <hip/hip_runtime.h>
#include <math.h>

#define NBATCH 16
#define NN 63

// One block per batch element. 1024 threads = 16 waves.
// FW/elementwise mapping: w = tid>>6, lane = tid&63 (= column j), rows i = w + 16m, m=0..3.
// Sinkhorn mapping: rr = tid>>4 (row), q = tid&15, cols c0..c0+3 (c0 = 4q).
// adj2: per row, label-sectioned byte list (word-padded, null=64).
// adj1: merged byte list (S-scan) + merged ushort list of precomputed Zf offsets
//       entry = (label-1)*4225 + k*65 (null = 16900 -> zero row of Zf).
__global__ __launch_bounds__(1024) void ged_kernel(
    const float* __restrict__ node_w, const float* __restrict__ edge_w,
    const int* __restrict__ A1g, const int* __restrict__ A2g,
    const int* __restrict__ l1g, const int* __restrict__ l2g,
    float* __restrict__ ged_out)
{
    const int b    = blockIdx.x;
    const int tid  = threadIdx.x;
    const int lane = tid & 63;
    const int w    = tid >> 6;

    __shared__ __align__(16) float XK[64*65];       // K then X, [row*65+col]; col 64 = 0
    __shared__ __align__(16) float Zf[4*4225 + 65]; // 4 Z planes [a*4225 + k*65 + j]; zero row @16900
    __shared__ __align__(16) float us[64];
    __shared__ __align__(16) float vs[64];
    __shared__ float rX[65], cXs[65];               // [64] = 0
    __shared__ float S1s[64], S2s[64];
    __shared__ __align__(16) float red[32];
    __shared__ float ncost[64];
    __shared__ float Qs[16];                        // Q[a*4+b] = 2*ec[a][b] - 2*eid
    __shared__ float cns[29], ces[7];
    __shared__ int   l1s[64], l2s[64];
    __shared__ __align__(4) unsigned char adjo1[64*8], adjo2[64*8];
    __shared__ __align__(4) unsigned char adj1e[64*64];    // merged byte list (S-scan)
    __shared__ __align__(4) unsigned char adj2e[64*80];    // sectioned byte list
    __shared__ __align__(4) unsigned short adj1u[64*64];   // merged Zf-offset list

    // ---- S0: prefill + small loads ----
    ((unsigned int*)adj1e)[tid] = 0x40404040u;                       // 1024 dw
    for (int t2 = tid; t2 < 1280; t2 += 1024) ((unsigned int*)adj2e)[t2] = 0x40404040u;
    for (int t2 = tid; t2 < 2048; t2 += 1024) ((unsigned int*)adj1u)[t2] = 0x42044204u; // 16900
    if (tid < 29) cns[tid] = fmaxf(node_w[tid], 0.f);
    else if (tid >= 32 && tid < 39) ces[tid-32] = fmaxf(edge_w[tid-32], 0.f);
    if (tid >= 64 && tid < 128) XK[(tid-64)*65 + 64] = 0.f;
    else if (tid >= 128 && tid < 193) Zf[16900 + (tid-128)] = 0.f;   // zero row
    if (tid == 40) { rX[64] = 0.f; cXs[64] = 0.f; }
    if (tid >= 320 && tid < 384) l1s[tid-320] = (tid-320 < NN) ? l1g[b*NN + tid-320] : 0;
    else if (tid >= 384 && tid < 448) l2s[tid-384] = (tid-384 < NN) ? l2g[b*NN + tid-384] : 0;
    __syncthreads();

    // ---- S1: ballot adjacency build + cost tables ----
    {
        const unsigned long long lt = (1ull << lane) - 1ull;
        #pragma unroll
        for (int r = 0; r < 8; ++r) {
            int g = (w << 3) + r;            // 0..127, wave-uniform
            int row = g & 63;
            if (g < 64) {                    // A2: sectioned byte list
                int v = 0;
                if (row < NN && lane < NN) v = A2g[((size_t)b * NN + row) * NN + lane];
                int base = 0;
                #pragma unroll
                for (int vv = 1; vv <= 4; ++vv) {
                    if (lane == 0) adjo2[row*8 + vv-1] = (unsigned char)base;
                    unsigned long long mv = __ballot(v == vv);
                    if (v == vv) adj2e[row*80 + base + __popcll(mv & lt)] = (unsigned char)lane;
                    base += __popcll(mv);
                    base = (base + 3) & ~3;
                }
                if (lane == 0) adjo2[row*8 + 4] = (unsigned char)base;
            } else {                         // A1: merged byte + ushort offset lists
                int v = 0;
                if (row < NN && lane < NN) v = A1g[((size_t)b * NN + row) * NN + lane];
                int base = 0;
                #pragma unroll
                for (int vv = 1; vv <= 4; ++vv) {
                    unsigned long long mv = __ballot(v == vv);
                    if (v == vv) {
                        int pos = row*64 + base + __popcll(mv & lt);
                        adj1e[pos] = (unsigned char)lane;
                        adj1u[pos] = (unsigned short)((vv-1)*4225 + lane*65);
                    }
                    base += __popcll(mv);
                }
                if (lane == 0) {
                    adjo1[row*8 + 4] = (unsigned char)((base + 3) & ~3);  // bytes (S-scan)
                    adjo1[row*8 + 5] = (unsigned char)((base + 1) >> 1);  // dwords (quad)
                }
            }
        }
    }
    if (tid < 64) {
        int r0 = tid >> 3, c1 = tid & 7;
        float vv = 0.f;
        if (r0 != c1) {
            int lo = min(r0, c1), hi = max(r0, c1);
            vv = cns[lo*7 - (lo*(lo-1))/2 + (hi-lo-1)];
        }
        ncost[tid] = vv;
    } else if (tid < 80) {
        int a = (tid-64) >> 2, b2 = tid & 3;
        float ec = 0.f;
        if (a != b2) {
            int lo = min(a, b2), hi = max(a, b2);
            ec = ces[lo*3 - (lo*(lo-1))/2 + (hi-lo-1)];
        }
        Qs[tid-64] = 2.f*ec - 2.f*ces[6];
    }
    __syncthreads();
    const float eid = ces[6];
    const float nid = cns[28];

    float Qreg[16];
    #pragma unroll
    for (int u2 = 0; u2 < 16; ++u2) Qreg[u2] = Qs[u2];

    // ---- c matrix in registers ----
    float c_reg[4];
    #pragma unroll
    for (int m = 0; m < 4; ++m) {
        int i = w + (m << 4);
        if (i < NN && lane < NN) c_reg[m] = ncost[(l1s[i] << 3) + l2s[lane]];
        else c_reg[m] = (i == NN && lane == NN) ? 0.f : nid;
    }

    const int q  = tid & 15;
    const int rr = tid >> 4;
    const int c0 = q << 2;
    float Krow[4], Kcol[4];

    auto grp_reduce = [&](float s) {
        s += __shfl_xor(s, 1, 64);
        s += __shfl_xor(s, 2, 64);
        s += __shfl_xor(s, 4, 64);
        s += __shfl_xor(s, 8, 64);
        return s;
    };

    // K = exp(-gval), fused u0 = 1/rowsum (row i lives in wave i&15's 64 lanes)
    auto expand_u0 = [&](const float* gval) {
        float rs[4];
        #pragma unroll
        for (int m = 0; m < 4; ++m) {
            int i = w + (m << 4);
            float val = __expf(-gval[m]);
            XK[i*65 + lane] = val;
            rs[m] = val;
        }
        #pragma unroll
        for (int m = 0; m < 4; ++m) {
            #pragma unroll
            for (int off = 1; off <= 32; off <<= 1) rs[m] += __shfl_xor(rs[m], off, 64);
        }
        if (lane == 0) {
            #pragma unroll
            for (int m = 0; m < 4; ++m) {
                int i = w + (m << 4);
                us[i] = (i < NN) ? __builtin_amdgcn_rcpf(rs[m]) : 1.f;
            }
        }
        __syncthreads();
    };

    // scaling-vector sinkhorn (u0 already in us): v = 1/(u^T K), u = 1/(K v)
    auto sinkhorn = [&](int iters) {
        #pragma unroll
        for (int u = 0; u < 4; ++u) {
            Krow[u] = XK[rr*65 + c0 + u];
            Kcol[u] = XK[(c0+u)*65 + rr];
        }
        for (int it = 0; it < iters; ++it) {
            {
                float4 u4 = *(const float4*)&us[c0];
                float t = grp_reduce(Kcol[0]*u4.x + Kcol[1]*u4.y + Kcol[2]*u4.z + Kcol[3]*u4.w);
                if (q == 0) vs[rr] = (rr < NN) ? __builtin_amdgcn_rcpf(t) : 1.f;
                __syncthreads();
            }
            if (it + 1 < iters) {
                float4 v4 = *(const float4*)&vs[c0];
                float t = grp_reduce(Krow[0]*v4.x + Krow[1]*v4.y + Krow[2]*v4.z + Krow[3]*v4.w);
                if (q == 0) us[rr] = (rr < NN) ? __builtin_amdgcn_rcpf(t) : 1.f;
                __syncthreads();
            }
        }
    };

    // materialize X = u*K*v into XK + row/col sums
    auto finalize = [&]() {
        float4 v4 = *(const float4*)&vs[c0];
        float4 u4 = *(const float4*)&us[c0];
        float uR = us[rr], vR = vs[rr];
        float sr = grp_reduce(Krow[0]*v4.x + Krow[1]*v4.y + Krow[2]*v4.z + Krow[3]*v4.w);
        float sc = grp_reduce(Kcol[0]*u4.x + Kcol[1]*u4.y + Kcol[2]*u4.z + Kcol[3]*u4.w);
        if (q == 0) { rX[rr] = uR * sr; cXs[rr] = vR * sc; }
        XK[rr*65 + c0 + 0] = uR * Krow[0] * v4.x;
        XK[rr*65 + c0 + 1] = uR * Krow[1] * v4.y;
        XK[rr*65 + c0 + 2] = uR * Krow[2] * v4.z;
        XK[rr*65 + c0 + 3] = uR * Krow[3] * v4.w;
        __syncthreads();
    };

    // S-scans (8 threads/row, word loop) + Y sections + write all 4 Z planes
    auto buildYZ_S = [&]() {
        {
            int row8 = tid >> 3, sub = tid & 7;
            int row = row8 & 63;
            const unsigned int* wp;
            const float* vsum;
            int nby;
            if (row8 < 64) { wp = (const unsigned int*)&adj2e[row*80]; nby = adjo2[row*8+4]; vsum = cXs; }
            else           { wp = (const unsigned int*)&adj1e[row*64]; nby = adjo1[row*8+4]; vsum = rX; }
            int nw = nby >> 2;
            float s = 0.f;
            for (int ww = sub; ww < nw; ww += 8) {
                unsigned int wd = wp[ww];
                s += vsum[wd & 0x7f] + vsum[(wd>>8) & 0x7f]
                   + vsum[(wd>>16) & 0x7f] + vsum[(wd>>24) & 0x7f];
            }
            s += __shfl_xor(s, 1, 64);
            s += __shfl_xor(s, 2, 64);
            s += __shfl_xor(s, 4, 64);
            if (sub == 0) { if (row8 < 64) S2s[row] = s; else S1s[row] = s; }
        }
        const int xb = lane * 65;
        #pragma unroll
        for (int m = 0; m < 4; ++m) {
            int j = w + (m << 4);
            const unsigned int* wp = (const unsigned int*)&adj2e[j*80];
            unsigned int ow0 = ((const unsigned int*)adjo2)[j*2];
            unsigned int ow1 = ((const unsigned int*)adjo2)[j*2+1];
            int w0 = (ow0 & 255) >> 2, w1 = ((ow0>>8) & 255) >> 2;
            int w2 = ((ow0>>16) & 255) >> 2, w3 = (ow0 >> 24) >> 2;
            int w4 = (ow1 & 255) >> 2;
            float a0 = 0.f, a1 = 0.f, a2 = 0.f, a3 = 0.f;
            for (int ww = w0; ww < w1; ++ww) {
                unsigned int wd = wp[ww];
                a0 += XK[xb + (wd & 0x7f)] + XK[xb + ((wd>>8) & 0x7f)]
                    + XK[xb + ((wd>>16) & 0x7f)] + XK[xb + ((wd>>24) & 0x7f)];
            }
            for (int ww = w1; ww < w2; ++ww) {
                unsigned int wd = wp[ww];
                a1 += XK[xb + (wd & 0x7f)] + XK[xb + ((wd>>8) & 0x7f)]
                    + XK[xb + ((wd>>16) & 0x7f)] + XK[xb + ((wd>>24) & 0x7f)];
            }
            for (int ww = w2; ww < w3; ++ww) {
                unsigned int wd = wp[ww];
                a2 += XK[xb + (wd & 0x7f)] + XK[xb + ((wd>>8) & 0x7f)]
                    + XK[xb + ((wd>>16) & 0x7f)] + XK[xb + ((wd>>24) & 0x7f)];
            }
            for (int ww = w3; ww < w4; ++ww) {
                unsigned int wd = wp[ww];
                a3 += XK[xb + (wd & 0x7f)] + XK[xb + ((wd>>8) & 0x7f)]
                    + XK[xb + ((wd>>16) & 0x7f)] + XK[xb + ((wd>>24) & 0x7f)];
            }
            int zb = xb + j;   // [k=lane][j]
            Zf[        zb] = Qreg[0] *a0 + Qreg[1] *a1 + Qreg[2] *a2 + Qreg[3] *a3;
            Zf[4225  + zb] = Qreg[4] *a0 + Qreg[5] *a1 + Qreg[6] *a2 + Qreg[7] *a3;
            Zf[8450  + zb] = Qreg[8] *a0 + Qreg[9] *a1 + Qreg[10]*a2 + Qreg[11]*a3;
            Zf[12675 + zb] = Qreg[12]*a0 + Qreg[13]*a1 + Qreg[14]*a2 + Qreg[15]*a3;
        }
        __syncthreads();
    };

    // quad: acc4[m] += sum over merged adj1 entries of Zf[entry + lane]
    auto quad = [&](float* acc4) {
        #pragma unroll
        for (int m = 0; m < 4; ++m) {
            int i = w + (m << 4);
            const unsigned int* wp = (const unsigned int*)&adj1u[i*64];
            int nw = adjo1[i*8+5];
            float acc = 0.f;
            #pragma unroll 2
            for (int ww = 0; ww < nw; ++ww) {
                unsigned int wd = wp[ww];
                acc += Zf[(wd & 0xffff) + lane] + Zf[(wd >> 16) + lane];
            }
            acc4[m] += acc;
        }
    };

    // ---- init: x0 = sinkhorn(exp(-c), 10); dx = D @ x0 ----
    expand_u0(c_reg);
    sinkhorn(10);
    finalize();
    buildYZ_S();
    float x[4], dx[4], bb4[4], gv[4];
    #pragma unroll
    for (int m = 0; m < 4; ++m) x[m] = XK[(w + (m<<4))*65 + lane];
    #pragma unroll
    for (int m = 0; m < 4; ++m) dx[m] = eid * (S1s[w + (m<<4)] + S2s[lane]);
    quad(dx);

    // ---- Frank-Wolfe iterations ----
    for (int it = 0; it < 15; ++it) {
        #pragma unroll
        for (int m = 0; m < 4; ++m) gv[m] = c_reg[m] + dx[m];
        expand_u0(gv);            // writes XK=K, us=u0; barrier inside
        sinkhorn(5);
        finalize();
        buildYZ_S();
        float db[4];
        #pragma unroll
        for (int m = 0; m < 4; ++m) bb4[m] = XK[(w + (m<<4))*65 + lane];
        #pragma unroll
        for (int m = 0; m < 4; ++m) db[m] = eid * (S1s[w + (m<<4)] + S2s[lane]);
        quad(db);
        // dn = d.(Db - Dx), nm = d.g
        float dn = 0.f, nm = 0.f;
        #pragma unroll
        for (int m = 0; m < 4; ++m) {
            float d = bb4[m] - x[m];
            dn += d * (db[m] - dx[m]);
            nm += d * gv[m];
        }
        #pragma unroll
        for (int off = 32; off >= 1; off >>= 1) {
            dn += __shfl_xor(dn, off, 64);
            nm += __shfl_xor(nm, off, 64);
        }
        if (lane == 0) { red[w] = dn; red[16 + w] = nm; }
        __syncthreads();
        const float4* r4 = (const float4*)red;
        float4 p0 = r4[0], p1 = r4[1], p2 = r4[2], p3 = r4[3];
        float4 p4 = r4[4], p5 = r4[5], p6 = r4[6], p7 = r4[7];
        float den = (p0.x+p0.y+p0.z+p0.w) + (p1.x+p1.y+p1.z+p1.w)
                  + (p2.x+p2.y+p2.z+p2.w) + (p3.x+p3.y+p3.z+p3.w);
        float num = (p4.x+p4.y+p4.z+p4.w) + (p5.x+p5.y+p5.z+p5.w)
                  + (p6.x+p6.y+p6.z+p6.w) + (p7.x+p7.y+p7.z+p7.w);
        float t;
        if (den > 0.f) t = fminf(fmaxf(-num / den, 0.f), 1.f);
        else           t = (num < 0.f) ? 1.f : 0.f;
        #pragma unroll
        for (int m = 0; m < 4; ++m) {
            float d = bb4[m] - x[m];
            x[m]  += t * d;
            dx[m] += t * (db[m] - dx[m]);   // D x_new tracked by linearity
        }
    }

    // ---- ged = 0.5 * x.Dx + c.x ----
    __syncthreads();   // red[] still being read above by other waves
    float g2 = 0.f;
    #pragma unroll
    for (int m = 0; m < 4; ++m) g2 += x[m] * (0.5f * dx[m] + c_reg[m]);
    #pragma unroll
    for (int off = 32; off >= 1; off >>= 1) g2 += __shfl_xor(g2, off, 64);
    if (lane == 0) red[w] = g2;
    __syncthreads();
    if (tid == 0) {
        float s = 0.f;
        #pragma unroll
        for (int u = 0; u < 16; ++u) s += red[u];
        ged_out[b] = s;
    }
}

__global__ void norm_kernel(const float* __restrict__ g, float* __restrict__ out) {
    int t = threadIdx.x;
    if (t < NBATCH) {
        float mn = g[0], mx = g[0];
        #pragma unroll
        for (int i = 1; i < NBATCH; ++i) { mn = fminf(mn, g[i]); mx = fmaxf(mx, g[i]); }
        out[t] = (g[t] - mn) / (mx - mn);
    }
}

extern "C" void kernel_launch(void* const* d_in, const int* in_sizes, int n_in,
                              void* d_out, int out_size, void* d_ws, size_t ws_size,
                              hipStream_t stream) {
    (void)in_sizes; (void)n_in; (void)out_size; (void)ws_size;
    const float* node_w = (const float*)d_in[0];
    const float* edge_w = (const float*)d_in[1];
    const int*   A1     = (const int*)d_in[2];
    const int*   A2     = (const int*)d_in[3];
    const int*   l1     = (const int*)d_in[4];
    const int*   l2     = (const int*)d_in[5];
    float* ged = (float*)d_ws;
    ged_kernel<<<dim3(NBATCH), dim3(1024), 0, stream>>>(node_w, edge_w, A1, A2, l1, l2, ged);
    norm_kernel<<<dim3(1), dim3(64), 0, stream>>>(ged, (float*)d_out);
}

// Round 7
// 152.016 us; speedup vs baseline: 5.9865x; 1.2044x over previous
//
#include <hip/hip_runtime.h>
#include <math.h>

#define NBATCH 16
#define NN 63

// One block per batch element. 1024 threads = 16 waves.
// FW mapping: w = tid>>6, lane = tid&63 (= column j), rows i = w + 16m, m=0..3.
// Sinkhorn mapping (waves 0-7 only): rr8 = tid>>3 (row/col 0..63), q8 = tid&7,
//   8 elements per thread (cols c8..c8+7, c8 = 8*q8), 3-step shfl reduce.
// adj2: per row, label-sectioned byte list (word-padded, null=64).
// adj1: merged ushort list of precomputed Zf offsets, entry = (label-1)*4225 + k*65
//   (null = 16900 -> zero row of Zf).
// S-terms: S2[j] = deg2(j) (col sums of X are exactly 1 after final col-normalize);
//   S1 folded into Zf via +eid*rX[k] per row k.
__global__ __launch_bounds__(1024) void ged_kernel(
    const float* __restrict__ node_w, const float* __restrict__ edge_w,
    const int* __restrict__ A1g, const int* __restrict__ A2g,
    const int* __restrict__ l1g, const int* __restrict__ l2g,
    float* __restrict__ ged_out)
{
    const int b    = blockIdx.x;
    const int tid  = threadIdx.x;
    const int lane = tid & 63;
    const int w    = tid >> 6;

    __shared__ __align__(16) float XK[64*65];       // K then X, [row*65+col]; col 64 = 0
    __shared__ __align__(16) float Zf[4*4225 + 65]; // 4 Z planes [a*4225 + k*65 + j]; zero row @16900
    __shared__ __align__(16) float us[64];
    __shared__ __align__(16) float vs[64];
    __shared__ float rX[64];
    __shared__ __align__(16) float red[32];
    __shared__ float ncost[64];
    __shared__ float Qs[16];                        // Q[a*4+b] = 2*ec[a][b] - 2*eid
    __shared__ float cns[29], ces[7];
    __shared__ float deg2f[64];
    __shared__ int   l1s[64], l2s[64];
    __shared__ __align__(4) unsigned char adjo2[64*8];     // padded section byte-offsets o0..o4
    __shared__ __align__(4) unsigned char adj2e[64*80];    // sectioned byte list
    __shared__ unsigned char adj1n[64];                    // dword count of adj1u row
    __shared__ __align__(4) unsigned short adj1u[64*64];   // merged Zf-offset list

    // ---- S0: prefill + small loads ----
    for (int t2 = tid; t2 < 1280; t2 += 1024) ((unsigned int*)adj2e)[t2] = 0x40404040u;
    for (int t2 = tid; t2 < 2048; t2 += 1024) ((unsigned int*)adj1u)[t2] = 0x42044204u; // 16900
    if (tid < 29) cns[tid] = fmaxf(node_w[tid], 0.f);
    else if (tid >= 32 && tid < 39) ces[tid-32] = fmaxf(edge_w[tid-32], 0.f);
    if (tid >= 64 && tid < 128) XK[(tid-64)*65 + 64] = 0.f;
    else if (tid >= 128 && tid < 192) Zf[16900 + (tid-128)] = 0.f;   // zero row (64 entries)
    if (tid >= 320 && tid < 384) l1s[tid-320] = (tid-320 < NN) ? l1g[b*NN + tid-320] : 0;
    else if (tid >= 384 && tid < 448) l2s[tid-384] = (tid-384 < NN) ? l2g[b*NN + tid-384] : 0;
    __syncthreads();

    // ---- S1: ballot adjacency build + cost tables ----
    {
        const unsigned long long lt = (1ull << lane) - 1ull;
        #pragma unroll
        for (int r = 0; r < 8; ++r) {
            int g = (w << 3) + r;            // 0..127, wave-uniform
            int row = g & 63;
            if (g < 64) {                    // A2: sectioned byte list + true degree
                int v = 0;
                if (row < NN && lane < NN) v = A2g[((size_t)b * NN + row) * NN + lane];
                int base = 0, tn = 0;
                #pragma unroll
                for (int vv = 1; vv <= 4; ++vv) {
                    if (lane == 0) adjo2[row*8 + vv-1] = (unsigned char)base;
                    unsigned long long mv = __ballot(v == vv);
                    if (v == vv) adj2e[row*80 + base + __popcll(mv & lt)] = (unsigned char)lane;
                    int c = __popcll(mv);
                    tn += c;
                    base = (base + c + 3) & ~3;
                }
                if (lane == 0) { adjo2[row*8 + 4] = (unsigned char)base; deg2f[row] = (float)tn; }
            } else {                         // A1: merged ushort Zf-offset list
                int v = 0;
                if (row < NN && lane < NN) v = A1g[((size_t)b * NN + row) * NN + lane];
                int base = 0;
                #pragma unroll
                for (int vv = 1; vv <= 4; ++vv) {
                    unsigned long long mv = __ballot(v == vv);
                    if (v == vv) {
                        int pos = row*64 + base + __popcll(mv & lt);
                        adj1u[pos] = (unsigned short)((vv-1)*4225 + lane*65);
                    }
                    base += __popcll(mv);
                }
                if (lane == 0) adj1n[row] = (unsigned char)((base + 1) >> 1);
            }
        }
    }
    if (tid < 64) {
        int r0 = tid >> 3, c1 = tid & 7;
        float vv = 0.f;
        if (r0 != c1) {
            int lo = min(r0, c1), hi = max(r0, c1);
            vv = cns[lo*7 - (lo*(lo-1))/2 + (hi-lo-1)];
        }
        ncost[tid] = vv;
    } else if (tid < 80) {
        int a = (tid-64) >> 2, b2 = tid & 3;
        float ec = 0.f;
        if (a != b2) {
            int lo = min(a, b2), hi = max(a, b2);
            ec = ces[lo*3 - (lo*(lo-1))/2 + (hi-lo-1)];
        }
        Qs[tid-64] = 2.f*ec - 2.f*ces[6];
    }
    __syncthreads();
    const float eid = ces[6];
    const float nid = cns[28];
    const float ed2 = eid * deg2f[lane];     // eid * S2[j=lane], constant over iterations

    float Qreg[16];
    #pragma unroll
    for (int u2 = 0; u2 < 16; ++u2) Qreg[u2] = Qs[u2];

    // ---- c matrix in registers ----
    float c_reg[4];
    #pragma unroll
    for (int m = 0; m < 4; ++m) {
        int i = w + (m << 4);
        if (i < NN && lane < NN) c_reg[m] = ncost[(l1s[i] << 3) + l2s[lane]];
        else c_reg[m] = (i == NN && lane == NN) ? 0.f : nid;
    }

    // ---- K = exp(-g) writer (pure, no reduction) ----
    auto expK = [&](const float* gval) {
        #pragma unroll
        for (int m = 0; m < 4; ++m)
            XK[(w + (m << 4))*65 + lane] = __expf(-gval[m]);
        __syncthreads();
    };

    // ---- sinkhorn on waves 0-7, 8 elems/thread ----
    const int q8  = tid & 7;
    const int rr8 = tid >> 3;     // 0..63 when w<8
    const int c8  = q8 << 3;
    float Krow[8], Kcol[8];

    auto red8 = [&](float s) {
        s += __shfl_xor(s, 1, 64);
        s += __shfl_xor(s, 2, 64);
        s += __shfl_xor(s, 4, 64);
        return s;
    };

    auto sink8 = [&](int iters) {
        if (w < 8) {
            #pragma unroll
            for (int u = 0; u < 8; ++u) {
                Krow[u] = XK[rr8*65 + c8 + u];
                Kcol[u] = XK[(c8+u)*65 + rr8];
            }
            float s = ((Krow[0]+Krow[1])+(Krow[2]+Krow[3]))+((Krow[4]+Krow[5])+(Krow[6]+Krow[7]));
            s = red8(s);                          // u1 = rcp(K . 1)
            if (q8 == 0) us[rr8] = (rr8 < NN) ? __builtin_amdgcn_rcpf(s) : 1.f;
        }
        __syncthreads();
        for (int it = 0; it < iters; ++it) {
            if (w < 8) {                          // v-update: t_c = sum_i K[i][c]*u_i
                float4 ua = *(const float4*)&us[c8], ub = *(const float4*)&us[c8+4];
                float t = ((Kcol[0]*ua.x + Kcol[1]*ua.y) + (Kcol[2]*ua.z + Kcol[3]*ua.w))
                        + ((Kcol[4]*ub.x + Kcol[5]*ub.y) + (Kcol[6]*ub.z + Kcol[7]*ub.w));
                t = red8(t);
                if (q8 == 0) vs[rr8] = (rr8 < NN) ? __builtin_amdgcn_rcpf(t) : 1.f;
            }
            __syncthreads();
            if (it + 1 < iters) {
                if (w < 8) {                      // u-update: t_r = sum_l K[r][l]*v_l
                    float4 va = *(const float4*)&vs[c8], vb = *(const float4*)&vs[c8+4];
                    float t = ((Krow[0]*va.x + Krow[1]*va.y) + (Krow[2]*va.z + Krow[3]*va.w))
                            + ((Krow[4]*vb.x + Krow[5]*vb.y) + (Krow[6]*vb.z + Krow[7]*vb.w));
                    t = red8(t);
                    if (q8 == 0) us[rr8] = (rr8 < NN) ? __builtin_amdgcn_rcpf(t) : 1.f;
                }
                __syncthreads();
            }
        }
    };

    // materialize X = u*K*v into XK + row sums rX (col sums are exactly 1)
    auto fin8 = [&]() {
        if (w < 8) {
            float4 va = *(const float4*)&vs[c8], vb = *(const float4*)&vs[c8+4];
            float uR = us[rr8];
            float p0 = Krow[0]*va.x, p1 = Krow[1]*va.y, p2 = Krow[2]*va.z, p3 = Krow[3]*va.w;
            float p4 = Krow[4]*vb.x, p5 = Krow[5]*vb.y, p6 = Krow[6]*vb.z, p7 = Krow[7]*vb.w;
            float sr = red8(((p0+p1)+(p2+p3)) + ((p4+p5)+(p6+p7)));
            if (q8 == 0) rX[rr8] = uR * sr;
            int xb8 = rr8*65 + c8;
            XK[xb8+0] = uR*p0; XK[xb8+1] = uR*p1; XK[xb8+2] = uR*p2; XK[xb8+3] = uR*p3;
            XK[xb8+4] = uR*p4; XK[xb8+5] = uR*p5; XK[xb8+6] = uR*p6; XK[xb8+7] = uR*p7;
        }
        __syncthreads();
    };

    // Y sections (word loops) + write all 4 Z planes with eid*rX fold
    auto buildYZ = [&]() {
        const int xb = lane * 65;
        const float eidrX = eid * rX[lane];
        #pragma unroll
        for (int m = 0; m < 4; ++m) {
            int j = w + (m << 4);
            const unsigned int* wp = (const unsigned int*)&adj2e[j*80];
            unsigned int ow0 = ((const unsigned int*)adjo2)[j*2];
            unsigned int ow1 = ((const unsigned int*)adjo2)[j*2+1];
            int w0 = (ow0 & 255) >> 2, w1 = ((ow0>>8) & 255) >> 2;
            int w2 = ((ow0>>16) & 255) >> 2, w3 = (ow0 >> 24) >> 2;
            int w4 = (ow1 & 255) >> 2;
            float a0 = 0.f, a1 = 0.f, a2 = 0.f, a3 = 0.f;
            for (int ww = w0; ww < w1; ++ww) {
                unsigned int wd = wp[ww];
                a0 += XK[xb + (wd & 0x7f)] + XK[xb + ((wd>>8) & 0x7f)]
                    + XK[xb + ((wd>>16) & 0x7f)] + XK[xb + ((wd>>24) & 0x7f)];
            }
            for (int ww = w1; ww < w2; ++ww) {
                unsigned int wd = wp[ww];
                a1 += XK[xb + (wd & 0x7f)] + XK[xb + ((wd>>8) & 0x7f)]
                    + XK[xb + ((wd>>16) & 0x7f)] + XK[xb + ((wd>>24) & 0x7f)];
            }
            for (int ww = w2; ww < w3; ++ww) {
                unsigned int wd = wp[ww];
                a2 += XK[xb + (wd & 0x7f)] + XK[xb + ((wd>>8) & 0x7f)]
                    + XK[xb + ((wd>>16) & 0x7f)] + XK[xb + ((wd>>24) & 0x7f)];
            }
            for (int ww = w3; ww < w4; ++ww) {
                unsigned int wd = wp[ww];
                a3 += XK[xb + (wd & 0x7f)] + XK[xb + ((wd>>8) & 0x7f)]
                    + XK[xb + ((wd>>16) & 0x7f)] + XK[xb + ((wd>>24) & 0x7f)];
            }
            int zb = xb + j;   // row k=lane, col j
            Zf[        zb] = Qreg[0] *a0 + Qreg[1] *a1 + Qreg[2] *a2 + Qreg[3] *a3 + eidrX;
            Zf[4225  + zb] = Qreg[4] *a0 + Qreg[5] *a1 + Qreg[6] *a2 + Qreg[7] *a3 + eidrX;
            Zf[8450  + zb] = Qreg[8] *a0 + Qreg[9] *a1 + Qreg[10]*a2 + Qreg[11]*a3 + eidrX;
            Zf[12675 + zb] = Qreg[12]*a0 + Qreg[13]*a1 + Qreg[14]*a2 + Qreg[15]*a3 + eidrX;
        }
        __syncthreads();
    };

    // quad: acc4[m] += sum over merged adj1 entries of Zf[entry + lane]
    auto quad = [&](float* acc4) {
        #pragma unroll
        for (int m = 0; m < 4; ++m) {
            int i = w + (m << 4);
            const unsigned int* wp = (const unsigned int*)&adj1u[i*64];
            int nw = adj1n[i];
            float acc = 0.f;
            #pragma unroll 2
            for (int ww = 0; ww < nw; ++ww) {
                unsigned int wd = wp[ww];
                acc += Zf[(wd & 0xffff) + lane] + Zf[(wd >> 16) + lane];
            }
            acc4[m] += acc;
        }
    };

    // ---- init: x0 = sinkhorn(exp(-c), 10); dx = D @ x0 ----
    expK(c_reg);
    sink8(10);
    fin8();
    buildYZ();
    float x[4], dx[4], bb4[4], gv[4];
    #pragma unroll
    for (int m = 0; m < 4; ++m) x[m] = XK[(w + (m<<4))*65 + lane];
    #pragma unroll
    for (int m = 0; m < 4; ++m) dx[m] = ed2;
    quad(dx);

    // ---- Frank-Wolfe iterations ----
    for (int it = 0; it < 15; ++it) {
        #pragma unroll
        for (int m = 0; m < 4; ++m) gv[m] = c_reg[m] + dx[m];
        expK(gv);
        sink8(5);
        fin8();
        buildYZ();
        float db[4];
        #pragma unroll
        for (int m = 0; m < 4; ++m) bb4[m] = XK[(w + (m<<4))*65 + lane];
        #pragma unroll
        for (int m = 0; m < 4; ++m) db[m] = ed2;
        quad(db);
        // dn = d.(Db - Dx), nm = d.g
        float dn = 0.f, nm = 0.f;
        #pragma unroll
        for (int m = 0; m < 4; ++m) {
            float d = bb4[m] - x[m];
            dn += d * (db[m] - dx[m]);
            nm += d * gv[m];
        }
        #pragma unroll
        for (int off = 32; off >= 1; off >>= 1) {
            dn += __shfl_xor(dn, off, 64);
            nm += __shfl_xor(nm, off, 64);
        }
        if (lane == 0) { red[w] = dn; red[16 + w] = nm; }
        __syncthreads();
        const float4* r4 = (const float4*)red;
        float4 p0 = r4[0], p1 = r4[1], p2 = r4[2], p3 = r4[3];
        float4 p4 = r4[4], p5 = r4[5], p6 = r4[6], p7 = r4[7];
        float den = (p0.x+p0.y+p0.z+p0.w) + (p1.x+p1.y+p1.z+p1.w)
                  + (p2.x+p2.y+p2.z+p2.w) + (p3.x+p3.y+p3.z+p3.w);
        float num = (p4.x+p4.y+p4.z+p4.w) + (p5.x+p5.y+p5.z+p5.w)
                  + (p6.x+p6.y+p6.z+p6.w) + (p7.x+p7.y+p7.z+p7.w);
        float t;
        if (den > 0.f) t = fminf(fmaxf(-num / den, 0.f), 1.f);
        else           t = (num < 0.f) ? 1.f : 0.f;
        #pragma unroll
        for (int m = 0; m < 4; ++m) {
            float d = bb4[m] - x[m];
            x[m]  += t * d;
            dx[m] += t * (db[m] - dx[m]);   // D x_new tracked by linearity
        }
    }

    // ---- ged = 0.5 * x.Dx + c.x ----
    __syncthreads();   // red[] still being read above by other waves
    float g2 = 0.f;
    #pragma unroll
    for (int m = 0; m < 4; ++m) g2 += x[m] * (0.5f * dx[m] + c_reg[m]);
    #pragma unroll
    for (int off = 32; off >= 1; off >>= 1) g2 += __shfl_xor(g2, off, 64);
    if (lane == 0) red[w] = g2;
    __syncthreads();
    if (tid == 0) {
        float s = 0.f;
        #pragma unroll
        for (int u = 0; u < 16; ++u) s += red[u];
        ged_out[b] = s;
    }
}

__global__ void norm_kernel(const float* __restrict__ g, float* __restrict__ out) {
    int t = threadIdx.x;
    if (t < NBATCH) {
        float mn = g[0], mx = g[0];
        #pragma unroll
        for (int i = 1; i < NBATCH; ++i) { mn = fminf(mn, g[i]); mx = fmaxf(mx, g[i]); }
        out[t] = (g[t] - mn) / (mx - mn);
    }
}

extern "C" void kernel_launch(void* const* d_in, const int* in_sizes, int n_in,
                              void* d_out, int out_size, void* d_ws, size_t ws_size,
                              hipStream_t stream) {
    (void)in_sizes; (void)n_in; (void)out_size; (void)ws_size;
    const float* node_w = (const float*)d_in[0];
    const float* edge_w = (const float*)d_in[1];
    const int*   A1     = (const int*)d_in[2];
    const int*   A2     = (const int*)d_in[3];
    const int*   l1     = (const int*)d_in[4];
    const int*   l2     = (const int*)d_in[5];
    float* ged = (float*)d_ws;
    ged_kernel<<<dim3(NBATCH), dim3(1024), 0, stream>>>(node_w, edge_w, A1, A2, l1, l2, ged);
    norm_kernel<<<dim3(1), dim3(64), 0, stream>>>(ged, (float*)d_out);
}

// Round 9
// 100.791 us; speedup vs baseline: 9.0290x; 1.5082x over previous
//
#include <hip/hip_runtime.h>
#include <math.h>

#define NBATCH 16
#define NN 63

typedef __attribute__((ext_vector_type(8))) short short8;
typedef __attribute__((ext_vector_type(4))) float f32x4;

__device__ __forceinline__ unsigned short f2bf(float f) {
    unsigned int u = __float_as_uint(f);
    u += 0x7fffu + ((u >> 16) & 1u);   // RNE
    return (unsigned short)(u >> 16);
}

// One block per batch element. 512 threads = 8 waves.
// Tile/slot mapping: wave w owns output tiles t = w and t = w+8; tile t ->
// (rt,ct) = (t>>2, t&3). Thread slot (s,r): i = rt*16 + (lane>>4)*4 + r,
// j = ct*16 + (lane&15)  — this is the MFMA D-fragment layout, so db comes
// out of M2 directly in FW-state registers.
// Sinkhorn mapping: rr8 = tid>>3 (row 0..63), q8 = tid&7, 8 elems/thread.
// Matvec: out = sum_a I1_a * X * W_a + I1any * (eid*rX) * 1^T  (+ eid*deg2[j]),
// W_a = sum_b Q[a][b]*I2_b — W/I planes are iteration-invariant bf16 in LDS.
__global__ __launch_bounds__(512) void ged_kernel(
    const float* __restrict__ node_w, const float* __restrict__ edge_w,
    const int* __restrict__ A1g, const int* __restrict__ A2g,
    const int* __restrict__ l1g, const int* __restrict__ l2g,
    float* __restrict__ ged_out)
{
    const int b    = blockIdx.x;
    const int tid  = threadIdx.x;
    const int lane = tid & 63;
    const int w    = tid >> 6;        // 0..7
    const int lr   = lane & 15;
    const int lg   = lane >> 4;

    __shared__ __align__(16) float XK[64*65];              // K then X, [row*65+col]
    __shared__ __align__(16) unsigned short Xb[64*72];     // X bf16, row-major
    __shared__ __align__(16) unsigned short Rb[4][64*72];  // R_a^T: [j][k]
    __shared__ __align__(16) unsigned short Wb[4][64*72];  // W_a (symmetric)
    __shared__ __align__(16) unsigned short I1b[4][64*72]; // I1_a (symmetric)
    __shared__ __align__(16) unsigned short I1any[64*72];  // any-label I1 (symmetric)
    __shared__ __align__(16) unsigned short rXb[64];       // bf16(eid * rowsum(X))
    __shared__ __align__(16) float us[64];
    __shared__ __align__(16) float vs[64];
    __shared__ __align__(16) float red[16];
    __shared__ float ncost[64];
    __shared__ float Qs[16];
    __shared__ unsigned short Qbf[20];                     // [a*5 + v], v=0 -> 0
    __shared__ float cns[29], ces[7];
    __shared__ float deg2f[64];
    __shared__ int l1s[64], l2s[64];

    // ---- phase A: weights + labels ----
    if (tid < 29) cns[tid] = fmaxf(node_w[tid], 0.f);
    else if (tid >= 32 && tid < 39) ces[tid-32] = fmaxf(edge_w[tid-32], 0.f);
    if (tid >= 64 && tid < 128) l1s[tid-64] = (tid-64 < NN) ? l1g[b*NN + tid-64] : 0;
    else if (tid >= 128 && tid < 192) l2s[tid-128] = (tid-128 < NN) ? l2g[b*NN + tid-128] : 0;
    __syncthreads();
    // ---- phase B: cost tables ----
    if (tid < 64) {
        int r0 = tid >> 3, c1 = tid & 7;
        float vv = 0.f;
        if (r0 != c1) {
            int lo = min(r0, c1), hi = max(r0, c1);
            vv = cns[lo*7 - (lo*(lo-1))/2 + (hi-lo-1)];
        }
        ncost[tid] = vv;
    } else if (tid < 80) {
        int a = (tid-64) >> 2, b2 = tid & 3;
        float ec = 0.f;
        if (a != b2) {
            int lo = min(a, b2), hi = max(a, b2);
            ec = ces[lo*3 - (lo*(lo-1))/2 + (hi-lo-1)];
        }
        float qv = 2.f*ec - 2.f*ces[6];
        Qs[tid-64] = qv;
        Qbf[a*5 + b2 + 1] = f2bf(qv);
    } else if (tid < 84) {
        Qbf[(tid-80)*5] = 0;
    }
    __syncthreads();
    // ---- phase C: build W/I1 planes + deg2 (rows >= NN stay zero) ----
    #pragma unroll
    for (int r = 0; r < 8; ++r) {
        int row = w + (r << 3);          // wave-uniform, covers 0..63
        int v2 = 0, v1 = 0;
        if (row < NN && lane < NN) {
            v2 = A2g[((size_t)b*NN + row)*NN + lane];
            v1 = A1g[((size_t)b*NN + row)*NN + lane];
        }
        int o = row*72 + lane;
        Wb[0][o] = Qbf[ 0 + v2];
        Wb[1][o] = Qbf[ 5 + v2];
        Wb[2][o] = Qbf[10 + v2];
        Wb[3][o] = Qbf[15 + v2];
        unsigned long long mv = __ballot(v2 != 0);
        if (lane == 0) deg2f[row] = (float)__popcll(mv);
        I1b[0][o] = (v1 == 1) ? 0x3F80 : 0;
        I1b[1][o] = (v1 == 2) ? 0x3F80 : 0;
        I1b[2][o] = (v1 == 3) ? 0x3F80 : 0;
        I1b[3][o] = (v1 == 4) ? 0x3F80 : 0;
        I1any[o]  = v1 ? 0x3F80 : 0;
    }
    __syncthreads();

    const float eid = ces[6];
    const float nid = cns[28];

    // ---- slot geometry ----
    int i0s[2], jcs[2], rts[2], cts[2];
    float ed2s[2];
    #pragma unroll
    for (int s = 0; s < 2; ++s) {
        int t = w + (s << 3);
        rts[s] = t >> 2; cts[s] = t & 3;
        i0s[s] = rts[s]*16 + lg*4;
        jcs[s] = cts[s]*16 + lr;
        ed2s[s] = eid * deg2f[jcs[s]];
    }

    float c_reg[2][4];
    #pragma unroll
    for (int s = 0; s < 2; ++s)
        #pragma unroll
        for (int r = 0; r < 4; ++r) {
            int i = i0s[s] + r, j = jcs[s];
            c_reg[s][r] = (i < NN && j < NN) ? ncost[(l1s[i] << 3) + l2s[j]]
                          : ((i == NN && j == NN) ? 0.f : nid);
        }

    const int q8  = tid & 7;
    const int rr8 = tid >> 3;     // 0..63
    const int c8  = q8 << 3;
    float Krow[8], Kcol[8];

    auto red8 = [&](float s) {
        s += __shfl_xor(s, 1, 64);
        s += __shfl_xor(s, 2, 64);
        s += __shfl_xor(s, 4, 64);
        return s;
    };

    // K = exp(-g) in D-fragment mapping
    auto expK = [&](float (*gv)[4]) {
        #pragma unroll
        for (int s = 0; s < 2; ++s)
            #pragma unroll
            for (int r = 0; r < 4; ++r)
                XK[(i0s[s] + r)*65 + jcs[s]] = __expf(-gv[s][r]);
        __syncthreads();
    };

    // scaling-vector sinkhorn: u0 = 1/rowsum, then v = 1/(u^T K), u = 1/(K v)
    auto sink8 = [&](int iters) {
        #pragma unroll
        for (int u = 0; u < 8; ++u) {
            Krow[u] = XK[rr8*65 + c8 + u];
            Kcol[u] = XK[(c8+u)*65 + rr8];
        }
        float s0 = ((Krow[0]+Krow[1])+(Krow[2]+Krow[3]))+((Krow[4]+Krow[5])+(Krow[6]+Krow[7]));
        s0 = red8(s0);
        if (q8 == 0) us[rr8] = (rr8 < NN) ? __builtin_amdgcn_rcpf(s0) : 1.f;
        __syncthreads();
        for (int it = 0; it < iters; ++it) {
            {
                float4 ua = *(const float4*)&us[c8], ub = *(const float4*)&us[c8+4];
                float t = ((Kcol[0]*ua.x + Kcol[1]*ua.y) + (Kcol[2]*ua.z + Kcol[3]*ua.w))
                        + ((Kcol[4]*ub.x + Kcol[5]*ub.y) + (Kcol[6]*ub.z + Kcol[7]*ub.w));
                t = red8(t);
                if (q8 == 0) vs[rr8] = (rr8 < NN) ? __builtin_amdgcn_rcpf(t) : 1.f;
            }
            __syncthreads();
            if (it + 1 < iters) {
                float4 va = *(const float4*)&vs[c8], vb = *(const float4*)&vs[c8+4];
                float t = ((Krow[0]*va.x + Krow[1]*va.y) + (Krow[2]*va.z + Krow[3]*va.w))
                        + ((Krow[4]*vb.x + Krow[5]*vb.y) + (Krow[6]*vb.z + Krow[7]*vb.w));
                t = red8(t);
                if (q8 == 0) us[rr8] = (rr8 < NN) ? __builtin_amdgcn_rcpf(t) : 1.f;
                __syncthreads();
            }
        }
    };

    // X = u*K*v into XK (f32) + Xb (bf16) + rXb = bf16(eid * rowsum)
    auto fin8 = [&]() {
        float4 va = *(const float4*)&vs[c8], vb = *(const float4*)&vs[c8+4];
        float uR = us[rr8];
        float p[8];
        p[0]=Krow[0]*va.x; p[1]=Krow[1]*va.y; p[2]=Krow[2]*va.z; p[3]=Krow[3]*va.w;
        p[4]=Krow[4]*vb.x; p[5]=Krow[5]*vb.y; p[6]=Krow[6]*vb.z; p[7]=Krow[7]*vb.w;
        float sr = red8(((p[0]+p[1])+(p[2]+p[3])) + ((p[4]+p[5])+(p[6]+p[7])));
        short8 xs;
        #pragma unroll
        for (int u = 0; u < 8; ++u) {
            float xv = uR * p[u];
            XK[rr8*65 + c8 + u] = xv;
            xs[u] = (short)f2bf(xv);
        }
        *(short8*)&Xb[rr8*72 + c8] = xs;
        if (q8 == 0) rXb[rr8] = f2bf(eid * (uR * sr));
        __syncthreads();
    };

    // M1: P_a = X * W_a (MFMA), write R_a^T bf16 into Rb
    auto M1R = [&]() {
        #pragma unroll
        for (int s = 0; s < 2; ++s) {
            const int rt = rts[s], ct = cts[s];
            f32x4 P0 = {0.f,0.f,0.f,0.f}, P1 = P0, P2 = P0, P3 = P0;
            #pragma unroll
            for (int kc = 0; kc < 2; ++kc) {
                const int fo = kc*32 + lg*8;
                short8 af = *(const short8*)&Xb[(rt*16 + lr)*72 + fo];
                const int bo = (ct*16 + lr)*72 + fo;
                P0 = __builtin_amdgcn_mfma_f32_16x16x32_bf16(af, *(const short8*)&Wb[0][bo], P0, 0,0,0);
                P1 = __builtin_amdgcn_mfma_f32_16x16x32_bf16(af, *(const short8*)&Wb[1][bo], P1, 0,0,0);
                P2 = __builtin_amdgcn_mfma_f32_16x16x32_bf16(af, *(const short8*)&Wb[2][bo], P2, 0,0,0);
                P3 = __builtin_amdgcn_mfma_f32_16x16x32_bf16(af, *(const short8*)&Wb[3][bo], P3, 0,0,0);
            }
            const int ro = (ct*16 + lr)*72 + rt*16 + lg*4;  // Rb[j][k0..k0+3]
            {
                unsigned long long v =  (unsigned long long)(f2bf(P0[0]) | ((unsigned)f2bf(P0[1])<<16))
                                     | ((unsigned long long)(f2bf(P0[2]) | ((unsigned)f2bf(P0[3])<<16)) << 32);
                *(unsigned long long*)&Rb[0][ro] = v;
            }
            {
                unsigned long long v =  (unsigned long long)(f2bf(P1[0]) | ((unsigned)f2bf(P1[1])<<16))
                                     | ((unsigned long long)(f2bf(P1[2]) | ((unsigned)f2bf(P1[3])<<16)) << 32);
                *(unsigned long long*)&Rb[1][ro] = v;
            }
            {
                unsigned long long v =  (unsigned long long)(f2bf(P2[0]) | ((unsigned)f2bf(P2[1])<<16))
                                     | ((unsigned long long)(f2bf(P2[2]) | ((unsigned)f2bf(P2[3])<<16)) << 32);
                *(unsigned long long*)&Rb[2][ro] = v;
            }
            {
                unsigned long long v =  (unsigned long long)(f2bf(P3[0]) | ((unsigned)f2bf(P3[1])<<16))
                                     | ((unsigned long long)(f2bf(P3[2]) | ((unsigned)f2bf(P3[3])<<16)) << 32);
                *(unsigned long long*)&Rb[3][ro] = v;
            }
        }
        __syncthreads();
    };

    // M2: out = sum_a I1_a * R_a + I1any * rXb  (db in D-frag regs)
    auto M2 = [&](float (*out)[4]) {
        #pragma unroll
        for (int s = 0; s < 2; ++s) {
            const int rt = rts[s], ct = cts[s];
            f32x4 acc = {0.f,0.f,0.f,0.f};
            #pragma unroll
            for (int a = 0; a < 4; ++a) {
                #pragma unroll
                for (int kc = 0; kc < 2; ++kc) {
                    const int fo = kc*32 + lg*8;
                    short8 af = *(const short8*)&I1b[a][(rt*16 + lr)*72 + fo];
                    short8 bf = *(const short8*)&Rb[a][(ct*16 + lr)*72 + fo];
                    acc = __builtin_amdgcn_mfma_f32_16x16x32_bf16(af, bf, acc, 0,0,0);
                }
            }
            #pragma unroll
            for (int kc = 0; kc < 2; ++kc) {
                const int fo = kc*32 + lg*8;
                short8 af = *(const short8*)&I1any[(rt*16 + lr)*72 + fo];
                short8 bf = *(const short8*)&rXb[fo];   // broadcast col-independent
                acc = __builtin_amdgcn_mfma_f32_16x16x32_bf16(af, bf, acc, 0,0,0);
            }
            #pragma unroll
            for (int r = 0; r < 4; ++r) out[s][r] = acc[r] + ed2s[s];
        }
    };

    // ---- init: x0 = sinkhorn(exp(-c), 10); dx = D @ x0 ----
    expK(c_reg);
    sink8(10);
    fin8();
    M1R();
    float x[2][4], dx[2][4], bb[2][4], gvv[2][4];
    M2(dx);
    #pragma unroll
    for (int s = 0; s < 2; ++s)
        #pragma unroll
        for (int r = 0; r < 4; ++r)
            x[s][r] = XK[(i0s[s] + r)*65 + jcs[s]];

    // ---- Frank-Wolfe iterations ----
    for (int it = 0; it < 15; ++it) {
        #pragma unroll
        for (int s = 0; s < 2; ++s)
            #pragma unroll
            for (int r = 0; r < 4; ++r)
                gvv[s][r] = c_reg[s][r] + dx[s][r];
        expK(gvv);
        sink8(5);
        fin8();
        M1R();
        float db[2][4];
        M2(db);
        #pragma unroll
        for (int s = 0; s < 2; ++s)
            #pragma unroll
            for (int r = 0; r < 4; ++r)
                bb[s][r] = XK[(i0s[s] + r)*65 + jcs[s]];
        float dn = 0.f, nm = 0.f;
        #pragma unroll
        for (int s = 0; s < 2; ++s)
            #pragma unroll
            for (int r = 0; r < 4; ++r) {
                float d = bb[s][r] - x[s][r];
                dn += d * (db[s][r] - dx[s][r]);
                nm += d * gvv[s][r];
            }
        #pragma unroll
        for (int off = 32; off >= 1; off >>= 1) {
            dn += __shfl_xor(dn, off, 64);
            nm += __shfl_xor(nm, off, 64);
        }
        if (lane == 0) { red[w] = dn; red[8 + w] = nm; }
        __syncthreads();
        float4 pa = *(const float4*)&red[0], pb = *(const float4*)&red[4];
        float4 pc = *(const float4*)&red[8], pd = *(const float4*)&red[12];
        float den = (pa.x+pa.y+pa.z+pa.w) + (pb.x+pb.y+pb.z+pb.w);
        float num = (pc.x+pc.y+pc.z+pc.w) + (pd.x+pd.y+pd.z+pd.w);
        float t;
        if (den > 0.f) t = fminf(fmaxf(-num / den, 0.f), 1.f);
        else           t = (num < 0.f) ? 1.f : 0.f;
        #pragma unroll
        for (int s = 0; s < 2; ++s)
            #pragma unroll
            for (int r = 0; r < 4; ++r) {
                float d = bb[s][r] - x[s][r];
                x[s][r]  += t * d;
                dx[s][r] += t * (db[s][r] - dx[s][r]);   // D x_new by linearity
            }
    }

    // ---- ged = 0.5 * x.Dx + c.x ----
    __syncthreads();   // red[] reads above complete before rewrite
    float g2 = 0.f;
    #pragma unroll
    for (int s = 0; s < 2; ++s)
        #pragma unroll
        for (int r = 0; r < 4; ++r)
            g2 += x[s][r] * (0.5f * dx[s][r] + c_reg[s][r]);
    #pragma unroll
    for (int off = 32; off >= 1; off >>= 1) g2 += __shfl_xor(g2, off, 64);
    if (lane == 0) red[w] = g2;
    __syncthreads();
    if (tid == 0) {
        float s = 0.f;
        #pragma unroll
        for (int u = 0; u < 8; ++u) s += red[u];
        ged_out[b] = s;
    }
}

__global__ void norm_kernel(const float* __restrict__ g, float* __restrict__ out) {
    int t = threadIdx.x;
    if (t < NBATCH) {
        float mn = g[0], mx = g[0];
        #pragma unroll
        for (int i = 1; i < NBATCH; ++i) { mn = fminf(mn, g[i]); mx = fmaxf(mx, g[i]); }
        out[t] = (g[t] - mn) / (mx - mn);
    }
}

extern "C" void kernel_launch(void* const* d_in, const int* in_sizes, int n_in,
                              void* d_out, int out_size, void* d_ws, size_t ws_size,
                              hipStream_t stream) {
    (void)in_sizes; (void)n_in; (void)out_size; (void)ws_size;
    const float* node_w = (const float*)d_in[0];
    const float* edge_w = (const float*)d_in[1];
    const int*   A1     = (const int*)d_in[2];
    const int*   A2     = (const int*)d_in[3];
    const int*   l1     = (const int*)d_in[4];
    const int*   l2     = (const int*)d_in[5];
    float* ged = (float*)d_ws;
    ged_kernel<<<dim3(NBATCH), dim3(512), 0, stream>>>(node_w, edge_w, A1, A2, l1, l2, ged);
    norm_kernel<<<dim3(1), dim3(64), 0, stream>>>(ged, (float*)d_out);
}

// Round 10
// 96.311 us; speedup vs baseline: 9.4490x; 1.0465x over previous
//
#include <hip/hip_runtime.h>
#include <math.h>

#define NBATCH 16
#define NN 63

typedef __attribute__((ext_vector_type(8))) short short8;
typedef __attribute__((ext_vector_type(4))) float f32x4;

__device__ __forceinline__ unsigned short f2bf(float f) {
    unsigned int u = __float_as_uint(f);
    u += 0x7fffu + ((u >> 16) & 1u);   // RNE
    return (unsigned short)(u >> 16);
}

// One block per batch element. 512 threads = 8 waves.
// Tile/slot mapping: wave w owns output tiles t = w and t = w+8; tile t ->
// (rt,ct) = (t>>2, t&3). Thread slot (s,r): i = rt*16 + (lane>>4)*4 + r,
// j = ct*16 + (lane&15)  — MFMA D-fragment layout = FW-state registers.
// Sinkhorn mapping: rr8 = tid>>3 (row 0..63), q8 = tid&7, 8 elems/thread.
// bf16 planes use FRAGMENT-MAJOR chunk layout: chunk((T,kc,lg,lr)) =
// ((T*2+kc)*4+lg)*16+lr, 8 shorts/chunk, so a wave's frag read is
// base+lane consecutive 16B chunks -> conflict-free ds_read_b128.
__global__ __launch_bounds__(512) void ged_kernel(
    const float* __restrict__ node_w, const float* __restrict__ edge_w,
    const int* __restrict__ A1g, const int* __restrict__ A2g,
    const int* __restrict__ l1g, const int* __restrict__ l2g,
    float* __restrict__ ged_out)
{
    const int b    = blockIdx.x;
    const int tid  = threadIdx.x;
    const int lane = tid & 63;
    const int w    = tid >> 6;        // 0..7
    const int lr   = lane & 15;
    const int lg   = lane >> 4;

    __shared__ __align__(16) float XK[64*65];              // K then X, [row*65+col]
    __shared__ __align__(16) unsigned short Xb[4096];      // X bf16, frag-major
    __shared__ __align__(16) unsigned short Rb[4][4096];   // R_a^T, frag-major
    __shared__ __align__(16) unsigned short Wb[4][4096];   // W_a, frag-major (symmetric)
    __shared__ __align__(16) unsigned short I1b[4][4096];  // I1_a, frag-major (symmetric)
    __shared__ __align__(16) unsigned short I1any[4096];   // any-label I1, frag-major
    __shared__ __align__(16) unsigned short rXb[64];       // bf16(eid * rowsum(X))
    __shared__ __align__(16) float us[64];
    __shared__ __align__(16) float vs[64];
    __shared__ __align__(16) float red[16];
    __shared__ float ncost[64];
    __shared__ unsigned short Qbf[20];                     // [a*5 + v], v=0 -> 0
    __shared__ float cns[29], ces[7];
    __shared__ float deg2f[64];
    __shared__ int l1s[64], l2s[64];

    // ---- phase A: weights + labels ----
    if (tid < 29) cns[tid] = fmaxf(node_w[tid], 0.f);
    else if (tid >= 32 && tid < 39) ces[tid-32] = fmaxf(edge_w[tid-32], 0.f);
    if (tid >= 64 && tid < 128) l1s[tid-64] = (tid-64 < NN) ? l1g[b*NN + tid-64] : 0;
    else if (tid >= 128 && tid < 192) l2s[tid-128] = (tid-128 < NN) ? l2g[b*NN + tid-128] : 0;
    __syncthreads();
    // ---- phase B: cost tables ----
    if (tid < 64) {
        int r0 = tid >> 3, c1 = tid & 7;
        float vv = 0.f;
        if (r0 != c1) {
            int lo = min(r0, c1), hi = max(r0, c1);
            vv = cns[lo*7 - (lo*(lo-1))/2 + (hi-lo-1)];
        }
        ncost[tid] = vv;
    } else if (tid < 80) {
        int a = (tid-64) >> 2, b2 = tid & 3;
        float ec = 0.f;
        if (a != b2) {
            int lo = min(a, b2), hi = max(a, b2);
            ec = ces[lo*3 - (lo*(lo-1))/2 + (hi-lo-1)];
        }
        Qbf[a*5 + b2 + 1] = f2bf(2.f*ec - 2.f*ces[6]);
    } else if (tid < 84) {
        Qbf[(tid-80)*5] = 0;
    }
    __syncthreads();
    // ---- phase C: build W/I1 planes (frag-major scatter) + deg2 ----
    #pragma unroll
    for (int r = 0; r < 8; ++r) {
        int row = w + (r << 3);          // wave-uniform, covers 0..63
        int v2 = 0, v1 = 0;
        if (row < NN && lane < NN) {
            v2 = A2g[((size_t)b*NN + row)*NN + lane];
            v1 = A1g[((size_t)b*NN + row)*NN + lane];
        }
        // frag address for element (row, col=lane):
        int T = row >> 4, lrr = row & 15;
        int kc = lane >> 5, lgg = (lane >> 3) & 3, e = lane & 7;
        int ci = ((((T<<1)+kc)*4 + lgg)*16 + lrr)*8 + e;
        Wb[0][ci] = Qbf[ 0 + v2];
        Wb[1][ci] = Qbf[ 5 + v2];
        Wb[2][ci] = Qbf[10 + v2];
        Wb[3][ci] = Qbf[15 + v2];
        unsigned long long mv = __ballot(v2 != 0);
        if (lane == 0) deg2f[row] = (float)__popcll(mv);
        I1b[0][ci] = (v1 == 1) ? 0x3F80 : 0;
        I1b[1][ci] = (v1 == 2) ? 0x3F80 : 0;
        I1b[2][ci] = (v1 == 3) ? 0x3F80 : 0;
        I1b[3][ci] = (v1 == 4) ? 0x3F80 : 0;
        I1any[ci]  = v1 ? 0x3F80 : 0;
    }
    __syncthreads();

    const float eid = ces[6];
    const float nid = cns[28];

    // ---- slot geometry ----
    int i0s[2], jcs[2], rts[2], cts[2];
    float ed2s[2];
    #pragma unroll
    for (int s = 0; s < 2; ++s) {
        int t = w + (s << 3);
        rts[s] = t >> 2; cts[s] = t & 3;
        i0s[s] = rts[s]*16 + lg*4;
        jcs[s] = cts[s]*16 + lr;
        ed2s[s] = eid * deg2f[jcs[s]];
    }

    float c_reg[2][4];
    #pragma unroll
    for (int s = 0; s < 2; ++s)
        #pragma unroll
        for (int r = 0; r < 4; ++r) {
            int i = i0s[s] + r, j = jcs[s];
            c_reg[s][r] = (i < NN && j < NN) ? ncost[(l1s[i] << 3) + l2s[j]]
                          : ((i == NN && j == NN) ? 0.f : nid);
        }

    const int q8  = tid & 7;
    const int rr8 = tid >> 3;     // 0..63
    const int c8  = q8 << 3;
    float Krow[8], Kcol[8];

    auto red8 = [&](float s) {
        s += __shfl_xor(s, 1, 64);
        s += __shfl_xor(s, 2, 64);
        s += __shfl_xor(s, 4, 64);
        return s;
    };

    // K = exp(-g) in D-fragment mapping
    auto expK = [&](float (*gv)[4]) {
        #pragma unroll
        for (int s = 0; s < 2; ++s)
            #pragma unroll
            for (int r = 0; r < 4; ++r)
                XK[(i0s[s] + r)*65 + jcs[s]] = __expf(-gv[s][r]);
        __syncthreads();
    };

    // scaling-vector sinkhorn: u0 = 1/rowsum, then v = 1/(u^T K), u = 1/(K v)
    auto sink8 = [&](int iters) {
        #pragma unroll
        for (int u = 0; u < 8; ++u) {
            Krow[u] = XK[rr8*65 + c8 + u];
            Kcol[u] = XK[(c8+u)*65 + rr8];
        }
        float s0 = ((Krow[0]+Krow[1])+(Krow[2]+Krow[3]))+((Krow[4]+Krow[5])+(Krow[6]+Krow[7]));
        s0 = red8(s0);
        if (q8 == 0) us[rr8] = (rr8 < NN) ? __builtin_amdgcn_rcpf(s0) : 1.f;
        __syncthreads();
        for (int it = 0; it < iters; ++it) {
            {
                float4 ua = *(const float4*)&us[c8], ub = *(const float4*)&us[c8+4];
                float t = ((Kcol[0]*ua.x + Kcol[1]*ua.y) + (Kcol[2]*ua.z + Kcol[3]*ua.w))
                        + ((Kcol[4]*ub.x + Kcol[5]*ub.y) + (Kcol[6]*ub.z + Kcol[7]*ub.w));
                t = red8(t);
                if (q8 == 0) vs[rr8] = (rr8 < NN) ? __builtin_amdgcn_rcpf(t) : 1.f;
            }
            __syncthreads();
            if (it + 1 < iters) {
                float4 va = *(const float4*)&vs[c8], vb = *(const float4*)&vs[c8+4];
                float t = ((Krow[0]*va.x + Krow[1]*va.y) + (Krow[2]*va.z + Krow[3]*va.w))
                        + ((Krow[4]*vb.x + Krow[5]*vb.y) + (Krow[6]*vb.z + Krow[7]*vb.w));
                t = red8(t);
                if (q8 == 0) us[rr8] = (rr8 < NN) ? __builtin_amdgcn_rcpf(t) : 1.f;
                __syncthreads();
            }
        }
    };

    // X = u*K*v into XK (f32) + Xb (bf16 frag chunk) + rXb
    auto fin8 = [&]() {
        float4 va = *(const float4*)&vs[c8], vb = *(const float4*)&vs[c8+4];
        float uR = us[rr8];
        float p[8];
        p[0]=Krow[0]*va.x; p[1]=Krow[1]*va.y; p[2]=Krow[2]*va.z; p[3]=Krow[3]*va.w;
        p[4]=Krow[4]*vb.x; p[5]=Krow[5]*vb.y; p[6]=Krow[6]*vb.z; p[7]=Krow[7]*vb.w;
        float sr = red8(((p[0]+p[1])+(p[2]+p[3])) + ((p[4]+p[5])+(p[6]+p[7])));
        short8 xs;
        #pragma unroll
        for (int u = 0; u < 8; ++u) {
            float xv = uR * p[u];
            XK[rr8*65 + c8 + u] = xv;
            xs[u] = (short)f2bf(xv);
        }
        // frag chunk: row rr8, cols c8..c8+7 -> T=rr8>>4, lr=rr8&15, kc=q8>>2, lg=q8&3
        int ci = (((((rr8>>4)<<1) + (q8>>2))*4 + (q8&3))*16 + (rr8&15)) << 3;
        *(short8*)&Xb[ci] = xs;
        if (q8 == 0) rXb[rr8] = f2bf(eid * (uR * sr));
        __syncthreads();
    };

    // M1: P_a = X * W_a (MFMA), write R_a^T bf16 into Rb (frag-major)
    auto M1R = [&]() {
        #pragma unroll
        for (int s = 0; s < 2; ++s) {
            const int rt = rts[s], ct = cts[s];
            f32x4 P0 = {0.f,0.f,0.f,0.f}, P1 = P0, P2 = P0, P3 = P0;
            #pragma unroll
            for (int kc = 0; kc < 2; ++kc) {
                const int ai = ((((rt<<1)+kc)*4 + lg)*16 + lr) << 3;   // Xb chunk
                const int bi = ((((ct<<1)+kc)*4 + lg)*16 + lr) << 3;   // Wb chunk
                short8 af = *(const short8*)&Xb[ai];
                P0 = __builtin_amdgcn_mfma_f32_16x16x32_bf16(af, *(const short8*)&Wb[0][bi], P0, 0,0,0);
                P1 = __builtin_amdgcn_mfma_f32_16x16x32_bf16(af, *(const short8*)&Wb[1][bi], P1, 0,0,0);
                P2 = __builtin_amdgcn_mfma_f32_16x16x32_bf16(af, *(const short8*)&Wb[2][bi], P2, 0,0,0);
                P3 = __builtin_amdgcn_mfma_f32_16x16x32_bf16(af, *(const short8*)&Wb[3][bi], P3, 0,0,0);
            }
            // R^T element (j = ct*16+lr, k = rt*16+lg*4+r):
            // chunk T=ct, kc=rt>>1, lg'=(rt&1)*2+(lg>>1), lr'=lr; e = (lg&1)*4+r
            const int cw = (((ct<<1) + (rt>>1))*4 + ((rt&1)*2 + (lg>>1)))*16 + lr;
            const int si = (cw << 3) + ((lg & 1) << 2);
            {
                unsigned long long v =  (unsigned long long)(f2bf(P0[0]) | ((unsigned)f2bf(P0[1])<<16))
                                     | ((unsigned long long)(f2bf(P0[2]) | ((unsigned)f2bf(P0[3])<<16)) << 32);
                *(unsigned long long*)&Rb[0][si] = v;
            }
            {
                unsigned long long v =  (unsigned long long)(f2bf(P1[0]) | ((unsigned)f2bf(P1[1])<<16))
                                     | ((unsigned long long)(f2bf(P1[2]) | ((unsigned)f2bf(P1[3])<<16)) << 32);
                *(unsigned long long*)&Rb[1][si] = v;
            }
            {
                unsigned long long v =  (unsigned long long)(f2bf(P2[0]) | ((unsigned)f2bf(P2[1])<<16))
                                     | ((unsigned long long)(f2bf(P2[2]) | ((unsigned)f2bf(P2[3])<<16)) << 32);
                *(unsigned long long*)&Rb[2][si] = v;
            }
            {
                unsigned long long v =  (unsigned long long)(f2bf(P3[0]) | ((unsigned)f2bf(P3[1])<<16))
                                     | ((unsigned long long)(f2bf(P3[2]) | ((unsigned)f2bf(P3[3])<<16)) << 32);
                *(unsigned long long*)&Rb[3][si] = v;
            }
        }
        __syncthreads();
    };

    // M2: out = sum_a I1_a * R_a + I1any * rXb  (db in D-frag regs)
    auto M2 = [&](float (*out)[4]) {
        #pragma unroll
        for (int s = 0; s < 2; ++s) {
            const int rt = rts[s], ct = cts[s];
            f32x4 acc = {0.f,0.f,0.f,0.f};
            #pragma unroll
            for (int kc = 0; kc < 2; ++kc) {
                const int ai = ((((rt<<1)+kc)*4 + lg)*16 + lr) << 3;   // I1 chunk
                const int bi = ((((ct<<1)+kc)*4 + lg)*16 + lr) << 3;   // Rb chunk
                #pragma unroll
                for (int a = 0; a < 4; ++a) {
                    short8 af = *(const short8*)&I1b[a][ai];
                    short8 bf = *(const short8*)&Rb[a][bi];
                    acc = __builtin_amdgcn_mfma_f32_16x16x32_bf16(af, bf, acc, 0,0,0);
                }
                short8 af = *(const short8*)&I1any[ai];
                short8 bf = *(const short8*)&rXb[kc*32 + lg*8];   // broadcast
                acc = __builtin_amdgcn_mfma_f32_16x16x32_bf16(af, bf, acc, 0,0,0);
            }
            #pragma unroll
            for (int r = 0; r < 4; ++r) out[s][r] = acc[r] + ed2s[s];
        }
    };

    // ---- init: x0 = sinkhorn(exp(-c), 10); dx = D @ x0 ----
    expK(c_reg);
    sink8(10);
    fin8();
    M1R();
    float x[2][4], dx[2][4], bb[2][4], gvv[2][4];
    M2(dx);
    #pragma unroll
    for (int s = 0; s < 2; ++s)
        #pragma unroll
        for (int r = 0; r < 4; ++r)
            x[s][r] = XK[(i0s[s] + r)*65 + jcs[s]];

    // ---- Frank-Wolfe iterations ----
    for (int it = 0; it < 15; ++it) {
        #pragma unroll
        for (int s = 0; s < 2; ++s)
            #pragma unroll
            for (int r = 0; r < 4; ++r)
                gvv[s][r] = c_reg[s][r] + dx[s][r];
        expK(gvv);
        sink8(5);
        fin8();
        M1R();
        float db[2][4];
        M2(db);
        #pragma unroll
        for (int s = 0; s < 2; ++s)
            #pragma unroll
            for (int r = 0; r < 4; ++r)
                bb[s][r] = XK[(i0s[s] + r)*65 + jcs[s]];
        float dn = 0.f, nm = 0.f;
        #pragma unroll
        for (int s = 0; s < 2; ++s)
            #pragma unroll
            for (int r = 0; r < 4; ++r) {
                float d = bb[s][r] - x[s][r];
                dn += d * (db[s][r] - dx[s][r]);
                nm += d * gvv[s][r];
            }
        #pragma unroll
        for (int off = 32; off >= 1; off >>= 1) {
            dn += __shfl_xor(dn, off, 64);
            nm += __shfl_xor(nm, off, 64);
        }
        if (lane == 0) { red[w] = dn; red[8 + w] = nm; }
        __syncthreads();
        float4 pa = *(const float4*)&red[0], pb = *(const float4*)&red[4];
        float4 pc = *(const float4*)&red[8], pd = *(const float4*)&red[12];
        float den = (pa.x+pa.y+pa.z+pa.w) + (pb.x+pb.y+pb.z+pb.w);
        float num = (pc.x+pc.y+pc.z+pc.w) + (pd.x+pd.y+pd.z+pd.w);
        float t;
        if (den > 0.f) t = fminf(fmaxf(-num / den, 0.f), 1.f);
        else           t = (num < 0.f) ? 1.f : 0.f;
        #pragma unroll
        for (int s = 0; s < 2; ++s)
            #pragma unroll
            for (int r = 0; r < 4; ++r) {
                float d = bb[s][r] - x[s][r];
                x[s][r]  += t * d;
                dx[s][r] += t * (db[s][r] - dx[s][r]);   // D x_new by linearity
            }
    }

    // ---- ged = 0.5 * x.Dx + c.x ----
    __syncthreads();   // red[] reads above complete before rewrite
    float g2 = 0.f;
    #pragma unroll
    for (int s = 0; s < 2; ++s)
        #pragma unroll
        for (int r = 0; r < 4; ++r)
            g2 += x[s][r] * (0.5f * dx[s][r] + c_reg[s][r]);
    #pragma unroll
    for (int off = 32; off >= 1; off >>= 1) g2 += __shfl_xor(g2, off, 64);
    if (lane == 0) red[w] = g2;
    __syncthreads();
    if (tid == 0) {
        float s = 0.f;
        #pragma unroll
        for (int u = 0; u < 8; ++u) s += red[u];
        ged_out[b] = s;
    }
}

__global__ void norm_kernel(const float* __restrict__ g, float* __restrict__ out) {
    int t = threadIdx.x;
    if (t < NBATCH) {
        float mn = g[0], mx = g[0];
        #pragma unroll
        for (int i = 1; i < NBATCH; ++i) { mn = fminf(mn, g[i]); mx = fmaxf(mx, g[i]); }
        out[t] = (g[t] - mn) / (mx - mn);
    }
}

extern "C" void kernel_launch(void* const* d_in, const int* in_sizes, int n_in,
                              void* d_out, int out_size, void* d_ws, size_t ws_size,
                              hipStream_t stream) {
    (void)in_sizes; (void)n_in; (void)out_size; (void)ws_size;
    const float* node_w = (const float*)d_in[0];
    const float* edge_w = (const float*)d_in[1];
    const int*   A1     = (const int*)d_in[2];
    const int*   A2     = (const int*)d_in[3];
    const int*   l1     = (const int*)d_in[4];
    const int*   l2     = (const int*)d_in[5];
    float* ged = (float*)d_ws;
    ged_kernel<<<dim3(NBATCH), dim3(512), 0, stream>>>(node_w, edge_w, A1, A2, l1, l2, ged);
    norm_kernel<<<dim3(1), dim3(64), 0, stream>>>(ged, (float*)d_out);
}

// Round 13
// 80.094 us; speedup vs baseline: 11.3622x; 1.2025x over previous
//
#include <hip/hip_runtime.h>
#include <math.h>

#define NBATCH 16
#define NN 63

typedef __attribute__((ext_vector_type(8))) short short8;
typedef __attribute__((ext_vector_type(4))) float f32x4;

__device__ __forceinline__ unsigned short f2bf(float f) {
    unsigned int u = __float_as_uint(f);
    u += 0x7fffu + ((u >> 16) & 1u);   // RNE
    return (unsigned short)(u >> 16);
}

// DPP add: s + dpp_move(s, CTRL) — VALU only, no DS-pipe traffic.
// CTRL must be a compile-time constant (template parameter).
template <int CTRL>
__device__ __forceinline__ float dpp_add(float s) {
    int si = __builtin_bit_cast(int, s);
    int t  = __builtin_amdgcn_update_dpp(si, si, CTRL, 0xF, 0xF, true);
    return s + __builtin_bit_cast(float, t);
}
// sum over each aligned 8-lane group: xor1 (quad_perm), xor2 (quad_perm),
// then xor7 (row_half_mirror) which adds the other quad's quad-sum.
__device__ __forceinline__ float red8_dpp(float s) {
    s = dpp_add<0xB1>(s);    // quad_perm [1,0,3,2]  (xor 1)
    s = dpp_add<0x4E>(s);    // quad_perm [2,3,0,1]  (xor 2)
    s = dpp_add<0x141>(s);   // row_half_mirror      (xor 7)
    return s;
}

// One block per batch element. 512 threads = 8 waves.
// Tile/slot mapping: wave w owns output tiles t = w and t = w+8; tile t ->
// (rt,ct) = (t>>2, t&3). Thread slot (s,r): i = rt*16 + (lane>>4)*4 + r,
// j = ct*16 + (lane&15)  — MFMA D-fragment layout = FW-state registers.
// Sinkhorn mapping: rr8 = tid>>3 (row 0..63), q8 = tid&7, 8 elems/thread.
// bf16 planes use fragment-major chunk layout (conflict-free b128 frag reads).
// Rank-1 term eid*rX*1^T is folded into R (I1any == sum_a I1_a, labels disjoint).
__global__ __launch_bounds__(512) void ged_kernel(
    const float* __restrict__ node_w, const float* __restrict__ edge_w,
    const int* __restrict__ A1g, const int* __restrict__ A2g,
    const int* __restrict__ l1g, const int* __restrict__ l2g,
    float* __restrict__ ged_out)
{
    const int b    = blockIdx.x;
    const int tid  = threadIdx.x;
    const int lane = tid & 63;
    const int w    = tid >> 6;        // 0..7
    const int lr   = lane & 15;
    const int lg   = lane >> 4;

    __shared__ __align__(16) float XK[64*65];              // K then X, [row*65+col]
    __shared__ __align__(16) unsigned short Xb[4096];      // X bf16, frag-major
    __shared__ __align__(16) unsigned short Rb[4][4096];   // R'_a^T, frag-major
    __shared__ __align__(16) unsigned short Wb[4][4096];   // W_a, frag-major (symmetric)
    __shared__ __align__(16) unsigned short I1b[4][4096];  // I1_a, frag-major (symmetric)
    __shared__ __align__(16) float rX[64];                 // rowsum(X)
    __shared__ __align__(16) float us[64];
    __shared__ __align__(16) float vs[64];
    __shared__ __align__(16) float red[16];
    __shared__ float ncost[64];
    __shared__ unsigned short Qbf[20];                     // [a*5 + v], v=0 -> 0
    __shared__ float cns[29], ces[7];
    __shared__ float deg2f[64];
    __shared__ int l1s[64], l2s[64];

    // ---- phase A: weights + labels ----
    if (tid < 29) cns[tid] = fmaxf(node_w[tid], 0.f);
    else if (tid >= 32 && tid < 39) ces[tid-32] = fmaxf(edge_w[tid-32], 0.f);
    if (tid >= 64 && tid < 128) l1s[tid-64] = (tid-64 < NN) ? l1g[b*NN + tid-64] : 0;
    else if (tid >= 128 && tid < 192) l2s[tid-128] = (tid-128 < NN) ? l2g[b*NN + tid-128] : 0;
    __syncthreads();
    // ---- phase B: cost tables ----
    if (tid < 64) {
        int r0 = tid >> 3, c1 = tid & 7;
        float vv = 0.f;
        if (r0 != c1) {
            int lo = min(r0, c1), hi = max(r0, c1);
            vv = cns[lo*7 - (lo*(lo-1))/2 + (hi-lo-1)];
        }
        ncost[tid] = vv;
    } else if (tid < 80) {
        int a = (tid-64) >> 2, b2 = tid & 3;
        float ec = 0.f;
        if (a != b2) {
            int lo = min(a, b2), hi = max(a, b2);
            ec = ces[lo*3 - (lo*(lo-1))/2 + (hi-lo-1)];
        }
        Qbf[a*5 + b2 + 1] = f2bf(2.f*ec - 2.f*ces[6]);
    } else if (tid < 84) {
        Qbf[(tid-80)*5] = 0;
    }
    __syncthreads();
    // ---- phase C: build W/I1 planes (frag-major scatter) + deg2 ----
    #pragma unroll
    for (int r = 0; r < 8; ++r) {
        int row = w + (r << 3);          // wave-uniform, covers 0..63
        int v2 = 0, v1 = 0;
        if (row < NN && lane < NN) {
            v2 = A2g[((size_t)b*NN + row)*NN + lane];
            v1 = A1g[((size_t)b*NN + row)*NN + lane];
        }
        // frag address for element (row, col=lane):
        int T = row >> 4, lrr = row & 15;
        int kc = lane >> 5, lgg = (lane >> 3) & 3, e = lane & 7;
        int ci = ((((T<<1)+kc)*4 + lgg)*16 + lrr)*8 + e;
        Wb[0][ci] = Qbf[ 0 + v2];
        Wb[1][ci] = Qbf[ 5 + v2];
        Wb[2][ci] = Qbf[10 + v2];
        Wb[3][ci] = Qbf[15 + v2];
        unsigned long long mv = __ballot(v2 != 0);
        if (lane == 0) deg2f[row] = (float)__popcll(mv);
        I1b[0][ci] = (v1 == 1) ? 0x3F80 : 0;
        I1b[1][ci] = (v1 == 2) ? 0x3F80 : 0;
        I1b[2][ci] = (v1 == 3) ? 0x3F80 : 0;
        I1b[3][ci] = (v1 == 4) ? 0x3F80 : 0;
    }
    __syncthreads();

    const float eid = ces[6];
    const float nid = cns[28];

    // ---- slot geometry ----
    int i0s[2], jcs[2], rts[2], cts[2];
    float ed2s[2];
    #pragma unroll
    for (int s = 0; s < 2; ++s) {
        int t = w + (s << 3);
        rts[s] = t >> 2; cts[s] = t & 3;
        i0s[s] = rts[s]*16 + lg*4;
        jcs[s] = cts[s]*16 + lr;
        ed2s[s] = eid * deg2f[jcs[s]];
    }

    float c_reg[2][4];
    #pragma unroll
    for (int s = 0; s < 2; ++s)
        #pragma unroll
        for (int r = 0; r < 4; ++r) {
            int i = i0s[s] + r, j = jcs[s];
            c_reg[s][r] = (i < NN && j < NN) ? ncost[(l1s[i] << 3) + l2s[j]]
                          : ((i == NN && j == NN) ? 0.f : nid);
        }

    const int q8  = tid & 7;
    const int rr8 = tid >> 3;     // 0..63
    const int c8  = q8 << 3;
    float Krow[8], Kcol[8];

    // K = exp(-g) in D-fragment mapping
    auto expK = [&](float (*gv)[4]) {
        #pragma unroll
        for (int s = 0; s < 2; ++s)
            #pragma unroll
            for (int r = 0; r < 4; ++r)
                XK[(i0s[s] + r)*65 + jcs[s]] = __expf(-gv[s][r]);
        __syncthreads();
    };

    // scaling-vector sinkhorn: u0 = 1/rowsum, then v = 1/(u^T K), u = 1/(K v)
    auto sink8 = [&](int iters) {
        #pragma unroll
        for (int u = 0; u < 8; ++u) {
            Krow[u] = XK[rr8*65 + c8 + u];
            Kcol[u] = XK[(c8+u)*65 + rr8];
        }
        float s0 = ((Krow[0]+Krow[1])+(Krow[2]+Krow[3]))+((Krow[4]+Krow[5])+(Krow[6]+Krow[7]));
        s0 = red8_dpp(s0);
        if (q8 == 0) us[rr8] = (rr8 < NN) ? __builtin_amdgcn_rcpf(s0) : 1.f;
        __syncthreads();
        for (int it = 0; it < iters; ++it) {
            {
                float4 ua = *(const float4*)&us[c8], ub = *(const float4*)&us[c8+4];
                float t = ((Kcol[0]*ua.x + Kcol[1]*ua.y) + (Kcol[2]*ua.z + Kcol[3]*ua.w))
                        + ((Kcol[4]*ub.x + Kcol[5]*ub.y) + (Kcol[6]*ub.z + Kcol[7]*ub.w));
                t = red8_dpp(t);
                if (q8 == 0) vs[rr8] = (rr8 < NN) ? __builtin_amdgcn_rcpf(t) : 1.f;
            }
            __syncthreads();
            if (it + 1 < iters) {
                float4 va = *(const float4*)&vs[c8], vb = *(const float4*)&vs[c8+4];
                float t = ((Krow[0]*va.x + Krow[1]*va.y) + (Krow[2]*va.z + Krow[3]*va.w))
                        + ((Krow[4]*vb.x + Krow[5]*vb.y) + (Krow[6]*vb.z + Krow[7]*vb.w));
                t = red8_dpp(t);
                if (q8 == 0) us[rr8] = (rr8 < NN) ? __builtin_amdgcn_rcpf(t) : 1.f;
                __syncthreads();
            }
        }
    };

    // X = u*K*v into XK (f32) + Xb (bf16 frag chunk) + rX (f32 rowsum)
    auto fin8 = [&]() {
        float4 va = *(const float4*)&vs[c8], vb = *(const float4*)&vs[c8+4];
        float uR = us[rr8];
        float p[8];
        p[0]=Krow[0]*va.x; p[1]=Krow[1]*va.y; p[2]=Krow[2]*va.z; p[3]=Krow[3]*va.w;
        p[4]=Krow[4]*vb.x; p[5]=Krow[5]*vb.y; p[6]=Krow[6]*vb.z; p[7]=Krow[7]*vb.w;
        float sr = red8_dpp(((p[0]+p[1])+(p[2]+p[3])) + ((p[4]+p[5])+(p[6]+p[7])));
        short8 xs;
        #pragma unroll
        for (int u = 0; u < 8; ++u) {
            float xv = uR * p[u];
            XK[rr8*65 + c8 + u] = xv;
            xs[u] = (short)f2bf(xv);
        }
        // frag chunk: row rr8, cols c8..c8+7 -> T=rr8>>4, lr=rr8&15, kc=q8>>2, lg=q8&3
        int ci = (((((rr8>>4)<<1) + (q8>>2))*4 + (q8&3))*16 + (rr8&15)) << 3;
        *(short8*)&Xb[ci] = xs;
        if (q8 == 0) rX[rr8] = uR * sr;
        __syncthreads();
    };

    // M1: P_a = X * W_a (MFMA) + eid*rX fold, write R'_a^T bf16 into Rb
    auto M1R = [&]() {
        #pragma unroll
        for (int s = 0; s < 2; ++s) {
            const int rt = rts[s], ct = cts[s];
            f32x4 P0 = {0.f,0.f,0.f,0.f}, P1 = P0, P2 = P0, P3 = P0;
            #pragma unroll
            for (int kc = 0; kc < 2; ++kc) {
                const int ai = ((((rt<<1)+kc)*4 + lg)*16 + lr) << 3;   // Xb chunk
                const int bi = ((((ct<<1)+kc)*4 + lg)*16 + lr) << 3;   // Wb chunk
                short8 af = *(const short8*)&Xb[ai];
                P0 = __builtin_amdgcn_mfma_f32_16x16x32_bf16(af, *(const short8*)&Wb[0][bi], P0, 0,0,0);
                P1 = __builtin_amdgcn_mfma_f32_16x16x32_bf16(af, *(const short8*)&Wb[1][bi], P1, 0,0,0);
                P2 = __builtin_amdgcn_mfma_f32_16x16x32_bf16(af, *(const short8*)&Wb[2][bi], P2, 0,0,0);
                P3 = __builtin_amdgcn_mfma_f32_16x16x32_bf16(af, *(const short8*)&Wb[3][bi], P3, 0,0,0);
            }
            // rank-1 fold: R'[k][j] = P[k][j] + eid*rX[k], k = i0s[s]+r (16B aligned)
            float4 rx4 = *(const float4*)&rX[i0s[s]];
            P0[0] += eid*rx4.x; P0[1] += eid*rx4.y; P0[2] += eid*rx4.z; P0[3] += eid*rx4.w;
            P1[0] += eid*rx4.x; P1[1] += eid*rx4.y; P1[2] += eid*rx4.z; P1[3] += eid*rx4.w;
            P2[0] += eid*rx4.x; P2[1] += eid*rx4.y; P2[2] += eid*rx4.z; P2[3] += eid*rx4.w;
            P3[0] += eid*rx4.x; P3[1] += eid*rx4.y; P3[2] += eid*rx4.z; P3[3] += eid*rx4.w;
            // R^T element (j = ct*16+lr, k = rt*16+lg*4+r):
            const int cw = (((ct<<1) + (rt>>1))*4 + ((rt&1)*2 + (lg>>1)))*16 + lr;
            const int si = (cw << 3) + ((lg & 1) << 2);
            {
                unsigned long long v =  (unsigned long long)(f2bf(P0[0]) | ((unsigned)f2bf(P0[1])<<16))
                                     | ((unsigned long long)(f2bf(P0[2]) | ((unsigned)f2bf(P0[3])<<16)) << 32);
                *(unsigned long long*)&Rb[0][si] = v;
            }
            {
                unsigned long long v =  (unsigned long long)(f2bf(P1[0]) | ((unsigned)f2bf(P1[1])<<16))
                                     | ((unsigned long long)(f2bf(P1[2]) | ((unsigned)f2bf(P1[3])<<16)) << 32);
                *(unsigned long long*)&Rb[1][si] = v;
            }
            {
                unsigned long long v =  (unsigned long long)(f2bf(P2[0]) | ((unsigned)f2bf(P2[1])<<16))
                                     | ((unsigned long long)(f2bf(P2[2]) | ((unsigned)f2bf(P2[3])<<16)) << 32);
                *(unsigned long long*)&Rb[2][si] = v;
            }
            {
                unsigned long long v =  (unsigned long long)(f2bf(P3[0]) | ((unsigned)f2bf(P3[1])<<16))
                                     | ((unsigned long long)(f2bf(P3[2]) | ((unsigned)f2bf(P3[3])<<16)) << 32);
                *(unsigned long long*)&Rb[3][si] = v;
            }
        }
        __syncthreads();
    };

    // M2: out = sum_a I1_a * R'_a  (+ eid*deg2), db in D-frag regs
    auto M2 = [&](float (*out)[4]) {
        #pragma unroll
        for (int s = 0; s < 2; ++s) {
            const int rt = rts[s], ct = cts[s];
            f32x4 acc = {0.f,0.f,0.f,0.f};
            #pragma unroll
            for (int kc = 0; kc < 2; ++kc) {
                const int ai = ((((rt<<1)+kc)*4 + lg)*16 + lr) << 3;   // I1 chunk
                const int bi = ((((ct<<1)+kc)*4 + lg)*16 + lr) << 3;   // Rb chunk
                #pragma unroll
                for (int a = 0; a < 4; ++a) {
                    short8 af = *(const short8*)&I1b[a][ai];
                    short8 bf = *(const short8*)&Rb[a][bi];
                    acc = __builtin_amdgcn_mfma_f32_16x16x32_bf16(af, bf, acc, 0,0,0);
                }
            }
            #pragma unroll
            for (int r = 0; r < 4; ++r) out[s][r] = acc[r] + ed2s[s];
        }
    };

    // ---- init: x0 = sinkhorn(exp(-c), 10); dx = D @ x0 ----
    expK(c_reg);
    sink8(10);
    fin8();
    M1R();
    float x[2][4], dx[2][4], bb[2][4], gvv[2][4];
    M2(dx);
    #pragma unroll
    for (int s = 0; s < 2; ++s)
        #pragma unroll
        for (int r = 0; r < 4; ++r)
            x[s][r] = XK[(i0s[s] + r)*65 + jcs[s]];

    // ---- Frank-Wolfe iterations ----
    for (int it = 0; it < 15; ++it) {
        #pragma unroll
        for (int s = 0; s < 2; ++s)
            #pragma unroll
            for (int r = 0; r < 4; ++r)
                gvv[s][r] = c_reg[s][r] + dx[s][r];
        expK(gvv);
        sink8(5);
        fin8();
        M1R();
        float db[2][4];
        M2(db);
        #pragma unroll
        for (int s = 0; s < 2; ++s)
            #pragma unroll
            for (int r = 0; r < 4; ++r)
                bb[s][r] = XK[(i0s[s] + r)*65 + jcs[s]];
        float dn = 0.f, nm = 0.f;
        #pragma unroll
        for (int s = 0; s < 2; ++s)
            #pragma unroll
            for (int r = 0; r < 4; ++r) {
                float d = bb[s][r] - x[s][r];
                dn += d * (db[s][r] - dx[s][r]);
                nm += d * gvv[s][r];
            }
        dn = red8_dpp(dn);  nm = red8_dpp(nm);       // 8-group sums on VALU
        dn += __shfl_xor(dn, 8, 64);  nm += __shfl_xor(nm, 8, 64);
        dn += __shfl_xor(dn, 16, 64); nm += __shfl_xor(nm, 16, 64);
        dn += __shfl_xor(dn, 32, 64); nm += __shfl_xor(nm, 32, 64);
        if (lane == 0) { red[w] = dn; red[8 + w] = nm; }
        __syncthreads();
        float4 pa = *(const float4*)&red[0], pb = *(const float4*)&red[4];
        float4 pc = *(const float4*)&red[8], pd = *(const float4*)&red[12];
        float den = (pa.x+pa.y+pa.z+pa.w) + (pb.x+pb.y+pb.z+pb.w);
        float num = (pc.x+pc.y+pc.z+pc.w) + (pd.x+pd.y+pd.z+pd.w);
        float t;
        if (den > 0.f) t = fminf(fmaxf(-num / den, 0.f), 1.f);
        else           t = (num < 0.f) ? 1.f : 0.f;
        #pragma unroll
        for (int s = 0; s < 2; ++s)
            #pragma unroll
            for (int r = 0; r < 4; ++r) {
                float d = bb[s][r] - x[s][r];
                x[s][r]  += t * d;
                dx[s][r] += t * (db[s][r] - dx[s][r]);   // D x_new by linearity
            }
    }

    // ---- ged = 0.5 * x.Dx + c.x ----
    __syncthreads();   // red[] reads above complete before rewrite
    float g2 = 0.f;
    #pragma unroll
    for (int s = 0; s < 2; ++s)
        #pragma unroll
        for (int r = 0; r < 4; ++r)
            g2 += x[s][r] * (0.5f * dx[s][r] + c_reg[s][r]);
    g2 = red8_dpp(g2);
    g2 += __shfl_xor(g2, 8, 64);
    g2 += __shfl_xor(g2, 16, 64);
    g2 += __shfl_xor(g2, 32, 64);
    if (lane == 0) red[w] = g2;
    __syncthreads();
    if (tid == 0) {
        float s = 0.f;
        #pragma unroll
        for (int u = 0; u < 8; ++u) s += red[u];
        ged_out[b] = s;
    }
}

__global__ void norm_kernel(const float* __restrict__ g, float* __restrict__ out) {
    int t = threadIdx.x;
    if (t < NBATCH) {
        float mn = g[0], mx = g[0];
        #pragma unroll
        for (int i = 1; i < NBATCH; ++i) { mn = fminf(mn, g[i]); mx = fmaxf(mx, g[i]); }
        out[t] = (g[t] - mn) / (mx - mn);
    }
}

extern "C" void kernel_launch(void* const* d_in, const int* in_sizes, int n_in,
                              void* d_out, int out_size, void* d_ws, size_t ws_size,
                              hipStream_t stream) {
    (void)in_sizes; (void)n_in; (void)out_size; (void)ws_size;
    const float* node_w = (const float*)d_in[0];
    const float* edge_w = (const float*)d_in[1];
    const int*   A1     = (const int*)d_in[2];
    const int*   A2     = (const int*)d_in[3];
    const int*   l1     = (const int*)d_in[4];
    const int*   l2     = (const int*)d_in[5];
    float* ged = (float*)d_ws;
    ged_kernel<<<dim3(NBATCH), dim3(512), 0, stream>>>(node_w, edge_w, A1, A2, l1, l2, ged);
    norm_kernel<<<dim3(1), dim3(64), 0, stream>>>(ged, (float*)d_out);
}